// Round 1
// baseline (1136.791 us; speedup 1.0000x reference)
//
#include <hip/hip_runtime.h>

#define NN 50000
#define NE 800000
#define DF 128
#define NG 256
#define NL 4
#define NOUTC 10
#define BN_EPS 1e-5f

static __device__ __forceinline__ float4 ld4(const float* p) { return *(const float4*)p; }

// ---------------------------------------------------------------- CSR build
__global__ void count_kernel(const int* __restrict__ ei, int* __restrict__ cnt)
{
    int e = blockIdx.x * blockDim.x + threadIdx.x;
    if (e < NE) atomicAdd(&cnt[ei[NE + e]], 1);   // dst = ei[1][e]
}

__global__ void scan1_kernel(const int* __restrict__ cnt, int* __restrict__ rowptr,
                             int* __restrict__ blksums)
{
    __shared__ int sdata[256];
    const int tid = threadIdx.x;
    const int base = blockIdx.x * 1024;
    int v[4]; int s = 0;
#pragma unroll
    for (int p = 0; p < 4; ++p) {
        int idx = base + tid * 4 + p;
        v[p] = (idx < NN) ? cnt[idx] : 0;
        s += v[p];
    }
    sdata[tid] = s;
    __syncthreads();
    for (int off = 1; off < 256; off <<= 1) {
        int t = (tid >= off) ? sdata[tid - off] : 0;
        __syncthreads();
        if (tid >= off) sdata[tid] += t;
        __syncthreads();
    }
    int run = (tid == 0) ? 0 : sdata[tid - 1];
#pragma unroll
    for (int p = 0; p < 4; ++p) {
        int idx = base + tid * 4 + p;
        if (idx < NN) rowptr[idx] = run;
        run += v[p];
    }
    if (tid == 255) blksums[blockIdx.x] = sdata[255];
}

__global__ void scan2_kernel(int* blksums, int nb)
{
    if (threadIdx.x == 0 && blockIdx.x == 0) {
        int run = 0;
        for (int i = 0; i < nb; ++i) { int t = blksums[i]; blksums[i] = run; run += t; }
    }
}

__global__ void scan3_kernel(int* __restrict__ rowptr, const int* __restrict__ blksums)
{
    int idx = blockIdx.x * blockDim.x + threadIdx.x;
    if (idx < NN) rowptr[idx] += blksums[idx >> 10];
    if (idx == 0) rowptr[NN] = NE;
}

__global__ void scatter_kernel(const int* __restrict__ ei, const int* __restrict__ rowptr,
                               int* __restrict__ fill, int* __restrict__ colidx)
{
    int e = blockIdx.x * blockDim.x + threadIdx.x;
    if (e < NE) {
        int d = ei[NE + e];
        int s = ei[e];
        int p = atomicAdd(&fill[d], 1);
        colidx[rowptr[d] + p] = s;
    }
}

__global__ void gstart_kernel(const int* __restrict__ batch, int* __restrict__ gstart)
{
    int g = blockIdx.x * blockDim.x + threadIdx.x;
    if (g > NG) return;
    if (g == NG) { gstart[NG] = NN; return; }
    int lo = 0, hi = NN;
    while (lo < hi) { int mid = (lo + hi) >> 1; if (batch[mid] < g) lo = mid + 1; else hi = mid; }
    gstart[g] = lo;
}

// ---------------------------------------------------------------- SpMM: t = x + A@x
__global__ __launch_bounds__(128)
void spmm_kernel(const float* __restrict__ x, const int* __restrict__ rowptr,
                 const int* __restrict__ colidx, float* __restrict__ t)
{
    const int i = blockIdx.x;
    const int f = threadIdx.x;
    float acc = x[i * DF + f];
    const int e0 = rowptr[i], e1 = rowptr[i + 1];
    for (int e = e0; e < e1; ++e) {
        int j = colidx[e];
        acc += x[j * DF + f];
    }
    t[i * DF + f] = acc;
}

// ---------------------------------------------------------------- GEMM1: h = t@W1 + b1, fused BN stats
__global__ __launch_bounds__(256)
void gemm1_kernel(const float* __restrict__ A, const float* __restrict__ W,
                  const float* __restrict__ bias, float* __restrict__ C,
                  float* __restrict__ stats)
{
    __shared__ float As[32][132];   // [k][row], padded
    __shared__ float Bs[32][128];   // [k][col]
    __shared__ float red[2][128];
    const int tid = threadIdx.x;
    const int tx = tid & 15, ty = tid >> 4;
    const int row0 = blockIdx.x * 128;
    float acc[8][8];
#pragma unroll
    for (int i = 0; i < 8; ++i)
#pragma unroll
        for (int j = 0; j < 8; ++j) acc[i][j] = 0.f;

    for (int k0 = 0; k0 < 128; k0 += 32) {
#pragma unroll
        for (int p = 0; p < 4; ++p) {
            int s = p * 256 + tid;
            int r = s >> 3;
            int c = (s & 7) << 2;
            float4 v = make_float4(0.f, 0.f, 0.f, 0.f);
            int grow = row0 + r;
            if (grow < NN) v = ld4(A + grow * DF + k0 + c);
            As[c + 0][r] = v.x; As[c + 1][r] = v.y; As[c + 2][r] = v.z; As[c + 3][r] = v.w;
        }
#pragma unroll
        for (int p = 0; p < 4; ++p) {
            int s = p * 256 + tid;
            int k = s >> 5;
            int c = (s & 31) << 2;
            *(float4*)(&Bs[k][c]) = ld4(W + (k0 + k) * DF + c);
        }
        __syncthreads();
#pragma unroll 8
        for (int k = 0; k < 32; ++k) {
            float4 a01 = *(const float4*)(&As[k][ty * 8]);
            float4 a23 = *(const float4*)(&As[k][ty * 8 + 4]);
            float a[8] = {a01.x, a01.y, a01.z, a01.w, a23.x, a23.y, a23.z, a23.w};
            float b[8];
#pragma unroll
            for (int j = 0; j < 8; ++j) b[j] = Bs[k][tx + j * 16];
#pragma unroll
            for (int i = 0; i < 8; ++i)
#pragma unroll
                for (int j = 0; j < 8; ++j) acc[i][j] = fmaf(a[i], b[j], acc[i][j]);
        }
        __syncthreads();
    }

    float bcol[8];
#pragma unroll
    for (int j = 0; j < 8; ++j) bcol[j] = bias[tx + j * 16];
    if (tid < 128) { red[0][tid] = 0.f; red[1][tid] = 0.f; }
    __syncthreads();
    float sj[8], qj[8];
#pragma unroll
    for (int j = 0; j < 8; ++j) { sj[j] = 0.f; qj[j] = 0.f; }
#pragma unroll
    for (int i = 0; i < 8; ++i) {
        int row = row0 + ty * 8 + i;
        if (row < NN) {
#pragma unroll
            for (int j = 0; j < 8; ++j) {
                float v = acc[i][j] + bcol[j];
                C[row * DF + tx + j * 16] = v;
                sj[j] += v; qj[j] += v * v;
            }
        }
    }
#pragma unroll
    for (int j = 0; j < 8; ++j) {
        atomicAdd(&red[0][tx + j * 16], sj[j]);
        atomicAdd(&red[1][tx + j * 16], qj[j]);
    }
    __syncthreads();
    if (tid < 128) {
        atomicAdd(&stats[tid], red[0][tid]);
        atomicAdd(&stats[128 + tid], red[1][tid]);
    }
}

// ---------------------------------------------------------------- GEMM2: x' = relu(bn(h))@W2 + b2
__global__ __launch_bounds__(256)
void gemm2_kernel(const float* __restrict__ Hm, const float* __restrict__ W,
                  const float* __restrict__ bias, const float* __restrict__ gamma,
                  const float* __restrict__ beta, const float* __restrict__ stats,
                  float* __restrict__ Xo)
{
    __shared__ float As[32][132];
    __shared__ float Bs[32][128];
    __shared__ float sscale[128], sshift[128];
    const int tid = threadIdx.x;
    const int tx = tid & 15, ty = tid >> 4;
    const int row0 = blockIdx.x * 128;
    if (tid < 128) {
        float s = stats[tid], q = stats[128 + tid];
        float mu = s * (1.f / NN);
        float var = q * (1.f / NN) - mu * mu;
        float sc = gamma[tid] * rsqrtf(var + BN_EPS);
        sscale[tid] = sc;
        sshift[tid] = beta[tid] - mu * sc;
    }
    __syncthreads();
    float acc[8][8];
#pragma unroll
    for (int i = 0; i < 8; ++i)
#pragma unroll
        for (int j = 0; j < 8; ++j) acc[i][j] = 0.f;

    for (int k0 = 0; k0 < 128; k0 += 32) {
#pragma unroll
        for (int p = 0; p < 4; ++p) {
            int s = p * 256 + tid;
            int r = s >> 3;
            int c = (s & 7) << 2;
            float4 v = make_float4(0.f, 0.f, 0.f, 0.f);
            int grow = row0 + r;
            if (grow < NN) v = ld4(Hm + grow * DF + k0 + c);
            int f = k0 + c;
            As[c + 0][r] = fmaxf(0.f, v.x * sscale[f + 0] + sshift[f + 0]);
            As[c + 1][r] = fmaxf(0.f, v.y * sscale[f + 1] + sshift[f + 1]);
            As[c + 2][r] = fmaxf(0.f, v.z * sscale[f + 2] + sshift[f + 2]);
            As[c + 3][r] = fmaxf(0.f, v.w * sscale[f + 3] + sshift[f + 3]);
        }
#pragma unroll
        for (int p = 0; p < 4; ++p) {
            int s = p * 256 + tid;
            int k = s >> 5;
            int c = (s & 31) << 2;
            *(float4*)(&Bs[k][c]) = ld4(W + (k0 + k) * DF + c);
        }
        __syncthreads();
#pragma unroll 8
        for (int k = 0; k < 32; ++k) {
            float4 a01 = *(const float4*)(&As[k][ty * 8]);
            float4 a23 = *(const float4*)(&As[k][ty * 8 + 4]);
            float a[8] = {a01.x, a01.y, a01.z, a01.w, a23.x, a23.y, a23.z, a23.w};
            float b[8];
#pragma unroll
            for (int j = 0; j < 8; ++j) b[j] = Bs[k][tx + j * 16];
#pragma unroll
            for (int i = 0; i < 8; ++i)
#pragma unroll
                for (int j = 0; j < 8; ++j) acc[i][j] = fmaf(a[i], b[j], acc[i][j]);
        }
        __syncthreads();
    }

    float bcol[8];
#pragma unroll
    for (int j = 0; j < 8; ++j) bcol[j] = bias[tx + j * 16];
#pragma unroll
    for (int i = 0; i < 8; ++i) {
        int row = row0 + ty * 8 + i;
        if (row < NN) {
#pragma unroll
            for (int j = 0; j < 8; ++j)
                Xo[row * DF + tx + j * 16] = acc[i][j] + bcol[j];
        }
    }
}

// ---------------------------------------------------------------- per-graph pooling
__global__ __launch_bounds__(128)
void pool_kernel(const float* __restrict__ xn, const int* __restrict__ gstart,
                 float* __restrict__ z, int l)
{
    const int g = blockIdx.x;
    const int f = threadIdx.x;
    const int r0 = gstart[g], r1 = gstart[g + 1];
    float acc = 0.f;
    for (int r = r0; r < r1; ++r) acc += xn[r * DF + f];
    z[g * (NL * DF) + l * DF + f] = acc;
}

// ---------------------------------------------------------------- final MLP
__global__ __launch_bounds__(128)
void p1_kernel(const float* __restrict__ z, const float* __restrict__ Wp1,
               const float* __restrict__ bp1, float* __restrict__ z1)
{
    const int g = blockIdx.x;
    const int f = threadIdx.x;
    float acc = bp1[f];
    for (int k = 0; k < NL * DF; ++k)
        acc = fmaf(z[g * (NL * DF) + k], Wp1[k * DF + f], acc);
    z1[g * DF + f] = acc;
}

__global__ __launch_bounds__(128)
void pbn_kernel(const float* __restrict__ z1, const float* __restrict__ gp,
                const float* __restrict__ bp, float* __restrict__ pstats)
{
    const int f = threadIdx.x;
    float s = 0.f, q = 0.f;
    for (int g = 0; g < NG; ++g) {
        float v = z1[g * DF + f];
        s += v; q += v * v;
    }
    float mu = s * (1.f / NG);
    float var = q * (1.f / NG) - mu * mu;
    float sc = gp[f] * rsqrtf(var + BN_EPS);
    pstats[f] = sc;
    pstats[DF + f] = bp[f] - mu * sc;
}

__global__ __launch_bounds__(128)
void p3_kernel(const float* __restrict__ z1, const float* __restrict__ pstats,
               const float* __restrict__ Wp2, const float* __restrict__ bp2,
               float* __restrict__ out)
{
    __shared__ float a[DF];
    const int g = blockIdx.x;
    const int f = threadIdx.x;
    float v = z1[g * DF + f];
    a[f] = fmaxf(0.f, v * pstats[f] + pstats[DF + f]);
    __syncthreads();
    if (f < NOUTC) {
        float acc = bp2[f];
        for (int k = 0; k < DF; ++k)
            acc = fmaf(a[k], Wp2[k * NOUTC + f], acc);
        out[g * NOUTC + f] = acc;
    }
}

// ---------------------------------------------------------------- launch
extern "C" void kernel_launch(void* const* d_in, const int* in_sizes, int n_in,
                              void* d_out, int out_size, void* d_ws, size_t ws_size,
                              hipStream_t stream)
{
    const float* d_x   = (const float*)d_in[0];
    const int*   d_ei  = (const int*)d_in[1];
    const int*   d_bat = (const int*)d_in[2];
    const float* d_W1  = (const float*)d_in[4];
    const float* d_b1  = (const float*)d_in[5];
    const float* d_gm  = (const float*)d_in[6];
    const float* d_bt  = (const float*)d_in[7];
    const float* d_W2  = (const float*)d_in[8];
    const float* d_b2  = (const float*)d_in[9];
    const float* d_Wp1 = (const float*)d_in[10];
    const float* d_bp1 = (const float*)d_in[11];
    const float* d_gp  = (const float*)d_in[12];
    const float* d_bp  = (const float*)d_in[13];
    const float* d_Wp2 = (const float*)d_in[14];
    const float* d_bp2 = (const float*)d_in[15];
    float* out = (float*)d_out;

    char* ws = (char*)d_ws;
    int*   cnt     = (int*)(ws + 0);          // N ints
    int*   rowptr  = (int*)(ws + 200192);     // N+1 ints
    int*   fill    = (int*)(ws + 400640);     // N ints
    int*   colidx  = (int*)(ws + 600832);     // E ints
    int*   blksums = (int*)(ws + 3800832);    // 64 ints
    int*   gstart  = (int*)(ws + 3801344);    // G+1 ints
    float* stats   = (float*)(ws + 3802624);  // 256 f32
    float* pstats  = (float*)(ws + 3803648);  // 256 f32
    float* zbuf    = (float*)(ws + 3804672);  // G*512 f32
    float* z1buf   = (float*)(ws + 4328960);  // G*128 f32
    float* xbuf    = (float*)(ws + 4460032);  // N*128 f32
    float* tbuf    = (float*)(ws + 30060032); // N*128 f32
    float* hbuf    = (float*)(ws + 55660032); // N*128 f32

    hipMemsetAsync(cnt, 0, NN * sizeof(int), stream);
    hipMemsetAsync(fill, 0, NN * sizeof(int), stream);
    count_kernel<<<(NE + 255) / 256, 256, 0, stream>>>(d_ei, cnt);
    scan1_kernel<<<49, 256, 0, stream>>>(cnt, rowptr, blksums);
    scan2_kernel<<<1, 64, 0, stream>>>(blksums, 49);
    scan3_kernel<<<(NN + 255) / 256, 256, 0, stream>>>(rowptr, blksums);
    scatter_kernel<<<(NE + 255) / 256, 256, 0, stream>>>(d_ei, rowptr, fill, colidx);
    gstart_kernel<<<2, 256, 0, stream>>>(d_bat, gstart);

    const int gemm_grid = (NN + 127) / 128;
    for (int l = 0; l < NL; ++l) {
        const float* xin = (l == 0) ? d_x : xbuf;
        spmm_kernel<<<NN, 128, 0, stream>>>(xin, rowptr, colidx, tbuf);
        hipMemsetAsync(stats, 0, 256 * sizeof(float), stream);
        gemm1_kernel<<<gemm_grid, 256, 0, stream>>>(tbuf, d_W1 + l * DF * DF,
                                                    d_b1 + l * DF, hbuf, stats);
        gemm2_kernel<<<gemm_grid, 256, 0, stream>>>(hbuf, d_W2 + l * DF * DF,
                                                    d_b2 + l * DF, d_gm + l * DF,
                                                    d_bt + l * DF, stats, xbuf);
        pool_kernel<<<NG, 128, 0, stream>>>(xbuf, gstart, zbuf, l);
    }
    p1_kernel<<<NG, 128, 0, stream>>>(zbuf, d_Wp1, d_bp1, z1buf);
    pbn_kernel<<<1, 128, 0, stream>>>(z1buf, d_gp, d_bp, pstats);
    p3_kernel<<<NG, 128, 0, stream>>>(z1buf, pstats, d_Wp2, d_bp2, out);
}

// Round 2
// 768.876 us; speedup vs baseline: 1.4785x; 1.4785x over previous
//
#include <hip/hip_runtime.h>

#define NN 50000
#define NE 800000
#define DF 128
#define NG 256
#define NL 4
#define NOUTC 10
#define BN_EPS 1e-5f

typedef __attribute__((ext_vector_type(8))) short bf16x8;
typedef __attribute__((ext_vector_type(4))) float f32x4;
typedef unsigned short ushort_t;

// split f32 into hi (truncated bf16) + lo (RNE bf16 of remainder)
static __device__ __forceinline__ void bsplit(float x, short& h, short& l)
{
    unsigned u = __float_as_uint(x);
    h = (short)(u >> 16);
    float rest = x - __uint_as_float(u & 0xffff0000u);
    unsigned r = __float_as_uint(rest);
    r += 0x7fffu + ((r >> 16) & 1u);
    l = (short)(r >> 16);
}

// ---------------------------------------------------------------- CSR build
__global__ void count_kernel(const int* __restrict__ ei, int* __restrict__ cnt)
{
    int e = blockIdx.x * blockDim.x + threadIdx.x;
    if (e < NE) atomicAdd(&cnt[ei[NE + e]], 1);   // dst = ei[1][e]
}

__global__ void scan1_kernel(const int* __restrict__ cnt, int* __restrict__ rowptr,
                             int* __restrict__ blksums)
{
    __shared__ int sdata[256];
    const int tid = threadIdx.x;
    const int base = blockIdx.x * 1024;
    int v[4]; int s = 0;
#pragma unroll
    for (int p = 0; p < 4; ++p) {
        int idx = base + tid * 4 + p;
        v[p] = (idx < NN) ? cnt[idx] : 0;
        s += v[p];
    }
    sdata[tid] = s;
    __syncthreads();
    for (int off = 1; off < 256; off <<= 1) {
        int t = (tid >= off) ? sdata[tid - off] : 0;
        __syncthreads();
        if (tid >= off) sdata[tid] += t;
        __syncthreads();
    }
    int run = (tid == 0) ? 0 : sdata[tid - 1];
#pragma unroll
    for (int p = 0; p < 4; ++p) {
        int idx = base + tid * 4 + p;
        if (idx < NN) rowptr[idx] = run;
        run += v[p];
    }
    if (tid == 255) blksums[blockIdx.x] = sdata[255];
}

__global__ void scan2_kernel(int* blksums, int nb)
{
    if (threadIdx.x == 0 && blockIdx.x == 0) {
        int run = 0;
        for (int i = 0; i < nb; ++i) { int t = blksums[i]; blksums[i] = run; run += t; }
    }
}

__global__ void scan3_kernel(int* __restrict__ rowptr, const int* __restrict__ blksums)
{
    int idx = blockIdx.x * blockDim.x + threadIdx.x;
    if (idx < NN) rowptr[idx] += blksums[idx >> 10];
    if (idx == 0) rowptr[NN] = NE;
}

__global__ void scatter_kernel(const int* __restrict__ ei, const int* __restrict__ rowptr,
                               int* __restrict__ fill, int* __restrict__ colidx)
{
    int e = blockIdx.x * blockDim.x + threadIdx.x;
    if (e < NE) {
        int d = ei[NE + e];
        int s = ei[e];
        int p = atomicAdd(&fill[d], 1);
        colidx[rowptr[d] + p] = s;
    }
}

__global__ void gstart_kernel(const int* __restrict__ batch, int* __restrict__ gstart)
{
    int g = blockIdx.x * blockDim.x + threadIdx.x;
    if (g > NG) return;
    if (g == NG) { gstart[NG] = NN; return; }
    int lo = 0, hi = NN;
    while (lo < hi) { int mid = (lo + hi) >> 1; if (batch[mid] < g) lo = mid + 1; else hi = mid; }
    gstart[g] = lo;
}

// ---------------------------------------------------------------- W -> fragment-ordered bf16 hi/lo blobs
// blob[m][nblk(8)][s(4)][lane(64)][j(8)], element = W[k][n],
// k = s*32 + (lane>>4)*8 + j, n = nblk*16 + (lane&15)
__global__ __launch_bounds__(64)
void wprep_kernel(const float* __restrict__ W1, const float* __restrict__ W2,
                  ushort_t* __restrict__ Bh, ushort_t* __restrict__ Bl)
{
    const int bid = blockIdx.x;           // 256 = 8 matrices * 8 nblk * 4 s
    const int m = bid >> 5;
    const int nblk = (bid >> 2) & 7;
    const int s = bid & 3;
    const int l = threadIdx.x;
    const float* Wsrc = (m < 4) ? (W1 + (size_t)m * DF * DF)
                                : (W2 + (size_t)(m - 4) * DF * DF);
    const int n = nblk * 16 + (l & 15);
    const int k0 = s * 32 + (l >> 4) * 8;
    size_t off = (size_t)m * (DF * DF) + ((size_t)(nblk * 4 + s) * 64 + l) * 8;
#pragma unroll
    for (int j = 0; j < 8; ++j) {
        float w = Wsrc[(size_t)(k0 + j) * DF + n];
        short h, lo;
        bsplit(w, h, lo);
        Bh[off + j] = (ushort_t)h;
        Bl[off + j] = (ushort_t)lo;
    }
}

// ---------------------------------------------------------------- SpMM: t = x + A@x (wave per node, 8-deep ILP)
__global__ __launch_bounds__(256)
void spmm_kernel(const float* __restrict__ x, const int* __restrict__ rowptr,
                 const int* __restrict__ colidx, float* __restrict__ t)
{
    const int lane = threadIdx.x & 63;
    const int i = __builtin_amdgcn_readfirstlane(blockIdx.x * 4 + (threadIdx.x >> 6));
    const float2* __restrict__ xr = (const float2*)x;
    float2 acc = xr[(size_t)i * 64 + lane];
    int e = rowptr[i];
    const int e1 = rowptr[i + 1];
    for (; e + 8 <= e1; e += 8) {
        int j0 = colidx[e + 0], j1 = colidx[e + 1], j2 = colidx[e + 2], j3 = colidx[e + 3];
        int j4 = colidx[e + 4], j5 = colidx[e + 5], j6 = colidx[e + 6], j7 = colidx[e + 7];
        float2 v0 = xr[(size_t)j0 * 64 + lane], v1 = xr[(size_t)j1 * 64 + lane];
        float2 v2 = xr[(size_t)j2 * 64 + lane], v3 = xr[(size_t)j3 * 64 + lane];
        float2 v4 = xr[(size_t)j4 * 64 + lane], v5 = xr[(size_t)j5 * 64 + lane];
        float2 v6 = xr[(size_t)j6 * 64 + lane], v7 = xr[(size_t)j7 * 64 + lane];
        acc.x += ((v0.x + v1.x) + (v2.x + v3.x)) + ((v4.x + v5.x) + (v6.x + v7.x));
        acc.y += ((v0.y + v1.y) + (v2.y + v3.y)) + ((v4.y + v5.y) + (v6.y + v7.y));
    }
    for (; e < e1; ++e) {
        int j = colidx[e];
        float2 v = xr[(size_t)j * 64 + lane];
        acc.x += v.x; acc.y += v.y;
    }
    ((float2*)t)[(size_t)i * 64 + lane] = acc;
}

// ---------------------------------------------------------------- GEMM1 (MFMA split-bf16): C = A@W + b, fused BN stats
__global__ __launch_bounds__(256)
void gemm1_kernel(const float* __restrict__ A, const ushort_t* __restrict__ Bh,
                  const ushort_t* __restrict__ Bl, const float* __restrict__ bias,
                  float* __restrict__ C, float* __restrict__ stats)
{
    __shared__ float red[2][DF];
    const int tid = threadIdx.x;
    const int lane = tid & 63;
    const int wave = tid >> 6;
    const int row0 = blockIdx.x * 64 + wave * 16;
    const int rA = row0 + (lane & 15);
    const int rAc = (rA < NN) ? rA : (NN - 1);
    const int kg = lane >> 4;

    if (tid < DF) { red[0][tid] = 0.f; red[1][tid] = 0.f; }
    __syncthreads();

    f32x4 acc[8];
#pragma unroll
    for (int f = 0; f < 8; ++f) acc[f] = (f32x4){0.f, 0.f, 0.f, 0.f};

#pragma unroll
    for (int s = 0; s < 4; ++s) {
        const float* ap = A + (size_t)rAc * DF + s * 32 + kg * 8;
        f32x4 a0 = *(const f32x4*)ap;
        f32x4 a1 = *(const f32x4*)(ap + 4);
        bf16x8 ah, al;
#pragma unroll
        for (int j = 0; j < 4; ++j) {
            short h, lo;
            bsplit(a0[j], h, lo); ah[j] = h; al[j] = lo;
            bsplit(a1[j], h, lo); ah[4 + j] = h; al[4 + j] = lo;
        }
#pragma unroll
        for (int f = 0; f < 8; ++f) {
            size_t boff = ((size_t)(f * 4 + s) * 64 + lane) * 8;
            bf16x8 bh = *(const bf16x8*)(Bh + boff);
            bf16x8 bl = *(const bf16x8*)(Bl + boff);
            acc[f] = __builtin_amdgcn_mfma_f32_16x16x32_bf16(ah, bh, acc[f], 0, 0, 0);
            acc[f] = __builtin_amdgcn_mfma_f32_16x16x32_bf16(al, bh, acc[f], 0, 0, 0);
            acc[f] = __builtin_amdgcn_mfma_f32_16x16x32_bf16(ah, bl, acc[f], 0, 0, 0);
        }
    }

    const int colb = lane & 15;
    const int rbase = row0 + kg * 4;
#pragma unroll
    for (int f = 0; f < 8; ++f) {
        int col = f * 16 + colb;
        float bcol = bias[col];
        float sj = 0.f, qj = 0.f;
#pragma unroll
        for (int r = 0; r < 4; ++r) {
            int row = rbase + r;
            if (row < NN) {
                float v = acc[f][r] + bcol;
                C[(size_t)row * DF + col] = v;
                sj += v; qj += v * v;
            }
        }
        atomicAdd(&red[0][col], sj);
        atomicAdd(&red[1][col], qj);
    }
    __syncthreads();
    if (tid < DF) {
        atomicAdd(&stats[tid], red[0][tid]);
        atomicAdd(&stats[DF + tid], red[1][tid]);
    }
}

// ---------------------------------------------------------------- GEMM2 (MFMA split-bf16): X = relu(bn(H))@W2 + b2
__global__ __launch_bounds__(256)
void gemm2_kernel(const float* __restrict__ Hm, const ushort_t* __restrict__ Bh,
                  const ushort_t* __restrict__ Bl, const float* __restrict__ bias,
                  const float* __restrict__ gamma, const float* __restrict__ beta,
                  const float* __restrict__ stats, float* __restrict__ Xo)
{
    __shared__ float sscale[DF], sshift[DF];
    const int tid = threadIdx.x;
    const int lane = tid & 63;
    const int wave = tid >> 6;
    const int row0 = blockIdx.x * 64 + wave * 16;
    const int rA = row0 + (lane & 15);
    const int rAc = (rA < NN) ? rA : (NN - 1);
    const int kg = lane >> 4;

    if (tid < DF) {
        float s = stats[tid], q = stats[DF + tid];
        float mu = s * (1.f / NN);
        float var = q * (1.f / NN) - mu * mu;
        float sc = gamma[tid] * rsqrtf(var + BN_EPS);
        sscale[tid] = sc;
        sshift[tid] = beta[tid] - mu * sc;
    }
    __syncthreads();

    f32x4 acc[8];
#pragma unroll
    for (int f = 0; f < 8; ++f) acc[f] = (f32x4){0.f, 0.f, 0.f, 0.f};

#pragma unroll
    for (int s = 0; s < 4; ++s) {
        const int kb = s * 32 + kg * 8;
        const float* ap = Hm + (size_t)rAc * DF + kb;
        f32x4 a0 = *(const f32x4*)ap;
        f32x4 a1 = *(const f32x4*)(ap + 4);
        f32x4 sc0 = *(const f32x4*)&sscale[kb];
        f32x4 sc1 = *(const f32x4*)&sscale[kb + 4];
        f32x4 sh0 = *(const f32x4*)&sshift[kb];
        f32x4 sh1 = *(const f32x4*)&sshift[kb + 4];
        bf16x8 ah, al;
#pragma unroll
        for (int j = 0; j < 4; ++j) {
            short h, lo;
            float v0 = fmaxf(0.f, a0[j] * sc0[j] + sh0[j]);
            float v1 = fmaxf(0.f, a1[j] * sc1[j] + sh1[j]);
            bsplit(v0, h, lo); ah[j] = h; al[j] = lo;
            bsplit(v1, h, lo); ah[4 + j] = h; al[4 + j] = lo;
        }
#pragma unroll
        for (int f = 0; f < 8; ++f) {
            size_t boff = ((size_t)(f * 4 + s) * 64 + lane) * 8;
            bf16x8 bh = *(const bf16x8*)(Bh + boff);
            bf16x8 bl = *(const bf16x8*)(Bl + boff);
            acc[f] = __builtin_amdgcn_mfma_f32_16x16x32_bf16(ah, bh, acc[f], 0, 0, 0);
            acc[f] = __builtin_amdgcn_mfma_f32_16x16x32_bf16(al, bh, acc[f], 0, 0, 0);
            acc[f] = __builtin_amdgcn_mfma_f32_16x16x32_bf16(ah, bl, acc[f], 0, 0, 0);
        }
    }

    const int colb = lane & 15;
    const int rbase = row0 + kg * 4;
#pragma unroll
    for (int f = 0; f < 8; ++f) {
        int col = f * 16 + colb;
        float bcol = bias[col];
#pragma unroll
        for (int r = 0; r < 4; ++r) {
            int row = rbase + r;
            if (row < NN)
                Xo[(size_t)row * DF + col] = acc[f][r] + bcol;
        }
    }
}

// ---------------------------------------------------------------- per-graph pooling (4 blocks/graph, unrolled)
__global__ __launch_bounds__(128)
void pool_kernel(const float* __restrict__ xn, const int* __restrict__ gstart,
                 float* __restrict__ z, int l)
{
    const int g = blockIdx.x >> 2;
    const int q = blockIdx.x & 3;
    const int f = threadIdx.x;
    const int r0 = gstart[g], r1 = gstart[g + 1];
    const int len = r1 - r0;
    const int qlen = (len + 3) >> 2;
    int r = r0 + q * qlen;
    int rend = r + qlen; if (rend > r1) rend = r1;
    float acc = 0.f;
    for (; r + 4 <= rend; r += 4) {
        float v0 = xn[(size_t)(r + 0) * DF + f], v1 = xn[(size_t)(r + 1) * DF + f];
        float v2 = xn[(size_t)(r + 2) * DF + f], v3 = xn[(size_t)(r + 3) * DF + f];
        acc += (v0 + v1) + (v2 + v3);
    }
    for (; r < rend; ++r) acc += xn[(size_t)r * DF + f];
    atomicAdd(&z[(size_t)g * (NL * DF) + l * DF + f], acc);
}

// ---------------------------------------------------------------- final MLP
__global__ __launch_bounds__(128)
void p1_kernel(const float* __restrict__ z, const float* __restrict__ Wp1,
               const float* __restrict__ bp1, float* __restrict__ z1)
{
    const int g = blockIdx.x;
    const int f = threadIdx.x;
    float acc = bp1[f];
    for (int k = 0; k < NL * DF; ++k)
        acc = fmaf(z[g * (NL * DF) + k], Wp1[k * DF + f], acc);
    z1[g * DF + f] = acc;
}

__global__ __launch_bounds__(128)
void pbn_kernel(const float* __restrict__ z1, const float* __restrict__ gp,
                const float* __restrict__ bp, float* __restrict__ pstats)
{
    const int f = threadIdx.x;
    float s = 0.f, q = 0.f;
    for (int g = 0; g < NG; ++g) {
        float v = z1[g * DF + f];
        s += v; q += v * v;
    }
    float mu = s * (1.f / NG);
    float var = q * (1.f / NG) - mu * mu;
    float sc = gp[f] * rsqrtf(var + BN_EPS);
    pstats[f] = sc;
    pstats[DF + f] = bp[f] - mu * sc;
}

__global__ __launch_bounds__(128)
void p3_kernel(const float* __restrict__ z1, const float* __restrict__ pstats,
               const float* __restrict__ Wp2, const float* __restrict__ bp2,
               float* __restrict__ out)
{
    __shared__ float a[DF];
    const int g = blockIdx.x;
    const int f = threadIdx.x;
    float v = z1[g * DF + f];
    a[f] = fmaxf(0.f, v * pstats[f] + pstats[DF + f]);
    __syncthreads();
    if (f < NOUTC) {
        float acc = bp2[f];
        for (int k = 0; k < DF; ++k)
            acc = fmaf(a[k], Wp2[k * NOUTC + f], acc);
        out[g * NOUTC + f] = acc;
    }
}

// ---------------------------------------------------------------- launch
extern "C" void kernel_launch(void* const* d_in, const int* in_sizes, int n_in,
                              void* d_out, int out_size, void* d_ws, size_t ws_size,
                              hipStream_t stream)
{
    const float* d_x   = (const float*)d_in[0];
    const int*   d_ei  = (const int*)d_in[1];
    const int*   d_bat = (const int*)d_in[2];
    const float* d_W1  = (const float*)d_in[4];
    const float* d_b1  = (const float*)d_in[5];
    const float* d_gm  = (const float*)d_in[6];
    const float* d_bt  = (const float*)d_in[7];
    const float* d_W2  = (const float*)d_in[8];
    const float* d_b2  = (const float*)d_in[9];
    const float* d_Wp1 = (const float*)d_in[10];
    const float* d_bp1 = (const float*)d_in[11];
    const float* d_gp  = (const float*)d_in[12];
    const float* d_bp  = (const float*)d_in[13];
    const float* d_Wp2 = (const float*)d_in[14];
    const float* d_bp2 = (const float*)d_in[15];
    float* out = (float*)d_out;

    char* ws = (char*)d_ws;
    int*      cnt     = (int*)(ws + 0);
    int*      rowptr  = (int*)(ws + 200192);
    int*      fill    = (int*)(ws + 400640);
    int*      colidx  = (int*)(ws + 600832);
    int*      blksums = (int*)(ws + 3800832);
    int*      gstart  = (int*)(ws + 3801344);
    float*    stats   = (float*)(ws + 3802624);
    float*    pstats  = (float*)(ws + 3803648);
    float*    zbuf    = (float*)(ws + 3804672);  // G*512
    float*    z1buf   = (float*)(ws + 4328960);  // G*128
    ushort_t* Whi     = (ushort_t*)(ws + 4460032); // 8*16384 bf16
    ushort_t* Wlo     = (ushort_t*)(ws + 4722176);
    float*    xbuf    = (float*)(ws + 4984320);  // N*128
    float*    tbuf    = (float*)(ws + 30584320); // N*128
    float*    hbuf    = (float*)(ws + 56184320); // N*128

    hipMemsetAsync(cnt, 0, NN * sizeof(int), stream);
    hipMemsetAsync(fill, 0, NN * sizeof(int), stream);
    hipMemsetAsync(zbuf, 0, NG * NL * DF * sizeof(float), stream);

    count_kernel<<<(NE + 255) / 256, 256, 0, stream>>>(d_ei, cnt);
    scan1_kernel<<<49, 256, 0, stream>>>(cnt, rowptr, blksums);
    scan2_kernel<<<1, 64, 0, stream>>>(blksums, 49);
    scan3_kernel<<<(NN + 255) / 256, 256, 0, stream>>>(rowptr, blksums);
    scatter_kernel<<<(NE + 255) / 256, 256, 0, stream>>>(d_ei, rowptr, fill, colidx);
    gstart_kernel<<<2, 256, 0, stream>>>(d_bat, gstart);
    wprep_kernel<<<256, 64, 0, stream>>>(d_W1, d_W2, Whi, Wlo);

    const int gemm_grid = (NN + 63) / 64;   // 782
    for (int l = 0; l < NL; ++l) {
        const float* xin = (l == 0) ? d_x : xbuf;
        spmm_kernel<<<(NN + 3) / 4, 256, 0, stream>>>(xin, rowptr, colidx, tbuf);
        hipMemsetAsync(stats, 0, 256 * sizeof(float), stream);
        gemm1_kernel<<<gemm_grid, 256, 0, stream>>>(tbuf,
                                                    Whi + (size_t)l * DF * DF,
                                                    Wlo + (size_t)l * DF * DF,
                                                    d_b1 + l * DF, hbuf, stats);
        gemm2_kernel<<<gemm_grid, 256, 0, stream>>>(hbuf,
                                                    Whi + (size_t)(4 + l) * DF * DF,
                                                    Wlo + (size_t)(4 + l) * DF * DF,
                                                    d_b2 + l * DF, d_gm + l * DF,
                                                    d_bt + l * DF, stats, xbuf);
        pool_kernel<<<NG * 4, 128, 0, stream>>>(xbuf, gstart, zbuf, l);
    }
    p1_kernel<<<NG, 128, 0, stream>>>(zbuf, d_Wp1, d_bp1, z1buf);
    pbn_kernel<<<1, 128, 0, stream>>>(z1buf, d_gp, d_bp, pstats);
    p3_kernel<<<NG, 128, 0, stream>>>(z1buf, pstats, d_Wp2, d_bp2, out);
}

// Round 3
// 590.411 us; speedup vs baseline: 1.9254x; 1.3023x over previous
//
#include <hip/hip_runtime.h>

#define NN 50000
#define NE 800000
#define DF 128
#define NG 256
#define NL 4
#define NOUTC 10
#define BN_EPS 1e-5f

typedef __attribute__((ext_vector_type(8))) short bf16x8;
typedef __attribute__((ext_vector_type(4))) float f32x4;
typedef unsigned short ushort_t;

static __device__ __forceinline__ float4 ld4(const float* p) { return *(const float4*)p; }

// RNE f32 -> bf16 bits
static __device__ __forceinline__ unsigned rne16(float x)
{
    unsigned u = __float_as_uint(x);
    return (u + 0x7fffu + ((u >> 16) & 1u)) >> 16;
}
// split f32 into hi (RNE bf16) + lo (RNE bf16 of remainder); hi+lo ~ exact
static __device__ __forceinline__ void bsplit(float x, unsigned& h, unsigned& l)
{
    h = rne16(x);
    float rest = x - __uint_as_float(h << 16);
    l = rne16(rest);
}

// ---------------------------------------------------------------- CSR build (counts in-place in rowptr)
__global__ void count_kernel(const int* __restrict__ ei, int* __restrict__ rowptr)
{
    int e = blockIdx.x * blockDim.x + threadIdx.x;
    if (e < NE) atomicAdd(&rowptr[ei[NE + e]], 1);   // dst = ei[1][e]
}

__global__ void scan1_kernel(int* __restrict__ rp, int* __restrict__ blksums)
{
    __shared__ int sdata[256];
    const int tid = threadIdx.x;
    const int base = blockIdx.x * 1024;
    int v[4]; int s = 0;
#pragma unroll
    for (int p = 0; p < 4; ++p) {
        int idx = base + tid * 4 + p;
        v[p] = (idx < NN) ? rp[idx] : 0;
        s += v[p];
    }
    sdata[tid] = s;
    __syncthreads();
    for (int off = 1; off < 256; off <<= 1) {
        int t = (tid >= off) ? sdata[tid - off] : 0;
        __syncthreads();
        if (tid >= off) sdata[tid] += t;
        __syncthreads();
    }
    int run = (tid == 0) ? 0 : sdata[tid - 1];
#pragma unroll
    for (int p = 0; p < 4; ++p) {
        int idx = base + tid * 4 + p;
        if (idx < NN) rp[idx] = run;
        run += v[p];
    }
    if (tid == 255) blksums[blockIdx.x] = sdata[255];
}

__global__ void scan2_kernel(int* blksums, int nb)
{
    if (threadIdx.x == 0 && blockIdx.x == 0) {
        int run = 0;
        for (int i = 0; i < nb; ++i) { int t = blksums[i]; blksums[i] = run; run += t; }
    }
}

__global__ void scan3_kernel(int* __restrict__ rowptr, const int* __restrict__ blksums)
{
    int idx = blockIdx.x * blockDim.x + threadIdx.x;
    if (idx < NN) rowptr[idx] += blksums[idx >> 10];
    if (idx == 0) rowptr[NN] = NE;
}

__global__ void scatter_kernel(const int* __restrict__ ei, const int* __restrict__ rowptr,
                               int* __restrict__ fill, int* __restrict__ colidx)
{
    int e = blockIdx.x * blockDim.x + threadIdx.x;
    if (e < NE) {
        int d = ei[NE + e];
        int s = ei[e];
        int p = atomicAdd(&fill[d], 1);
        colidx[rowptr[d] + p] = s;
    }
}

__global__ void gstart_kernel(const int* __restrict__ batch, int* __restrict__ gstart)
{
    int g = blockIdx.x * blockDim.x + threadIdx.x;
    if (g > NG) return;
    if (g == NG) { gstart[NG] = NN; return; }
    int lo = 0, hi = NN;
    while (lo < hi) { int mid = (lo + hi) >> 1; if (batch[mid] < g) lo = mid + 1; else hi = mid; }
    gstart[g] = lo;
}

// ---------------------------------------------------------------- W -> fragment-ordered bf16 hi/lo blobs
// blob[m][nblk(8)][s(4)][lane(64)][j(8)], element = W[k][n], k = s*32+(lane>>4)*8+j, n = nblk*16+(lane&15)
__global__ __launch_bounds__(64)
void wprep_kernel(const float* __restrict__ W1, const float* __restrict__ W2,
                  ushort_t* __restrict__ Bh, ushort_t* __restrict__ Bl)
{
    const int bid = blockIdx.x;           // 256 = 8 matrices * 8 nblk * 4 s
    const int m = bid >> 5;
    const int nblk = (bid >> 2) & 7;
    const int s = bid & 3;
    const int l = threadIdx.x;
    const float* Wsrc = (m < 4) ? (W1 + (size_t)m * DF * DF)
                                : (W2 + (size_t)(m - 4) * DF * DF);
    const int n = nblk * 16 + (l & 15);
    const int k0 = s * 32 + (l >> 4) * 8;
    size_t off = (size_t)m * (DF * DF) + ((size_t)(nblk * 4 + s) * 64 + l) * 8;
#pragma unroll
    for (int j = 0; j < 8; ++j) {
        float w = Wsrc[(size_t)(k0 + j) * DF + n];
        unsigned h, lo;
        bsplit(w, h, lo);
        Bh[off + j] = (ushort_t)h;
        Bl[off + j] = (ushort_t)lo;
    }
}

// ---------------------------------------------------------------- x (f32) -> bf16
__global__ __launch_bounds__(256)
void xtob16_kernel(const float* __restrict__ x, ushort_t* __restrict__ xh)
{
    size_t idx = ((size_t)blockIdx.x * 256 + threadIdx.x) * 4;
    float4 v = ld4(x + idx);
    unsigned p0 = rne16(v.x) | (rne16(v.y) << 16);
    unsigned p1 = rne16(v.z) | (rne16(v.w) << 16);
    uint2 pv; pv.x = p0; pv.y = p1;
    *(uint2*)(xh + idx) = pv;
}

// ---------------------------------------------------------------- SpMM: t = x + A@x (bf16 gather, f32 acc, hi/lo out)
template<int K>
static __device__ __forceinline__ void gatherK(const ushort_t* __restrict__ xh,
                                               const int* __restrict__ colidx,
                                               int e, int c2, float& ax, float& ay)
{
    unsigned v[K];
#pragma unroll
    for (int k = 0; k < K; ++k) {
        int j = colidx[e + k];
        v[k] = *(const unsigned*)(xh + (size_t)j * DF + c2);
    }
#pragma unroll
    for (int k = 0; k < K; ++k) {
        ax += __uint_as_float(v[k] << 16);
        ay += __uint_as_float(v[k] & 0xffff0000u);
    }
}

__global__ __launch_bounds__(256)
void spmm_kernel(const ushort_t* __restrict__ xh, const int* __restrict__ rowptr,
                 const int* __restrict__ colidx, ushort_t* __restrict__ th,
                 ushort_t* __restrict__ tl)
{
    const int lane = threadIdx.x & 63;
    const int i = __builtin_amdgcn_readfirstlane(blockIdx.x * 4 + (threadIdx.x >> 6));
    const int c2 = lane * 2;
    unsigned sv = *(const unsigned*)(xh + (size_t)i * DF + c2);
    float ax = __uint_as_float(sv << 16);
    float ay = __uint_as_float(sv & 0xffff0000u);
    int e = rowptr[i];
    const int e1 = rowptr[i + 1];
    for (; e + 16 <= e1; e += 16) gatherK<16>(xh, colidx, e, c2, ax, ay);
    if (e1 - e >= 8) { gatherK<8>(xh, colidx, e, c2, ax, ay); e += 8; }
    if (e1 - e >= 4) { gatherK<4>(xh, colidx, e, c2, ax, ay); e += 4; }
    if (e1 - e >= 2) { gatherK<2>(xh, colidx, e, c2, ax, ay); e += 2; }
    if (e1 - e >= 1) { gatherK<1>(xh, colidx, e, c2, ax, ay); }
    unsigned h0, l0, h1, l1;
    bsplit(ax, h0, l0);
    bsplit(ay, h1, l1);
    *(unsigned*)(th + (size_t)i * DF + c2) = h0 | (h1 << 16);
    *(unsigned*)(tl + (size_t)i * DF + c2) = l0 | (l1 << 16);
}

// ---------------------------------------------------------------- GEMM1: h = t@W1 + b1, fused BN stats
// 32 rows/wave (2 row-groups), A-frags direct from th/tl, 3-MFMA split precision
__global__ __launch_bounds__(256)
void gemm1_kernel(const ushort_t* __restrict__ th, const ushort_t* __restrict__ tl,
                  const ushort_t* __restrict__ Bh, const ushort_t* __restrict__ Bl,
                  const float* __restrict__ bias, float* __restrict__ C,
                  float* __restrict__ stats)
{
    __shared__ float red[2][DF];
    const int tid = threadIdx.x;
    const int lane = tid & 63;
    const int wave = tid >> 6;
    const int row0 = blockIdx.x * 128 + wave * 32;
    const int rA0 = row0 + (lane & 15);
    const int rAc0 = (rA0 < NN) ? rA0 : (NN - 1);
    const int rA1 = rA0 + 16;
    const int rAc1 = (rA1 < NN) ? rA1 : (NN - 1);
    const int kg = lane >> 4;

    if (tid < DF) { red[0][tid] = 0.f; red[1][tid] = 0.f; }
    __syncthreads();

    f32x4 acc0[8], acc1[8];
#pragma unroll
    for (int f = 0; f < 8; ++f) {
        acc0[f] = (f32x4){0.f, 0.f, 0.f, 0.f};
        acc1[f] = (f32x4){0.f, 0.f, 0.f, 0.f};
    }

    for (int s = 0; s < 4; ++s) {
        const int ko = s * 32 + kg * 8;
        bf16x8 ah0 = *(const bf16x8*)(th + (size_t)rAc0 * DF + ko);
        bf16x8 al0 = *(const bf16x8*)(tl + (size_t)rAc0 * DF + ko);
        bf16x8 ah1 = *(const bf16x8*)(th + (size_t)rAc1 * DF + ko);
        bf16x8 al1 = *(const bf16x8*)(tl + (size_t)rAc1 * DF + ko);
#pragma unroll
        for (int f = 0; f < 8; ++f) {
            const size_t boff = ((size_t)(f * 4 + s) * 64 + lane) * 8;
            bf16x8 bh = *(const bf16x8*)(Bh + boff);
            bf16x8 bl = *(const bf16x8*)(Bl + boff);
            acc0[f] = __builtin_amdgcn_mfma_f32_16x16x32_bf16(ah0, bh, acc0[f], 0, 0, 0);
            acc0[f] = __builtin_amdgcn_mfma_f32_16x16x32_bf16(al0, bh, acc0[f], 0, 0, 0);
            acc0[f] = __builtin_amdgcn_mfma_f32_16x16x32_bf16(ah0, bl, acc0[f], 0, 0, 0);
            acc1[f] = __builtin_amdgcn_mfma_f32_16x16x32_bf16(ah1, bh, acc1[f], 0, 0, 0);
            acc1[f] = __builtin_amdgcn_mfma_f32_16x16x32_bf16(al1, bh, acc1[f], 0, 0, 0);
            acc1[f] = __builtin_amdgcn_mfma_f32_16x16x32_bf16(ah1, bl, acc1[f], 0, 0, 0);
        }
    }

    const int colb = lane & 15;
    const int rb0 = row0 + kg * 4;
    const int rb1 = row0 + 16 + kg * 4;
#pragma unroll
    for (int f = 0; f < 8; ++f) {
        const int col = f * 16 + colb;
        const float bcol = bias[col];
        float sj = 0.f, qj = 0.f;
#pragma unroll
        for (int r = 0; r < 4; ++r) {
            int row = rb0 + r;
            if (row < NN) {
                float v = acc0[f][r] + bcol;
                C[(size_t)row * DF + col] = v;
                sj += v; qj += v * v;
            }
        }
#pragma unroll
        for (int r = 0; r < 4; ++r) {
            int row = rb1 + r;
            if (row < NN) {
                float v = acc1[f][r] + bcol;
                C[(size_t)row * DF + col] = v;
                sj += v; qj += v * v;
            }
        }
        atomicAdd(&red[0][col], sj);
        atomicAdd(&red[1][col], qj);
    }
    __syncthreads();
    if (tid < DF) {
        atomicAdd(&stats[tid], red[0][tid]);
        atomicAdd(&stats[DF + tid], red[1][tid]);
    }
}

// ---------------------------------------------------------------- GEMM2: x' = relu(bn(h))@W2 + b2, fused pool, bf16 out
__global__ __launch_bounds__(256)
void gemm2_kernel(const float* __restrict__ Hm, const ushort_t* __restrict__ Bh,
                  const ushort_t* __restrict__ Bl, const float* __restrict__ bias,
                  const float* __restrict__ gamma, const float* __restrict__ beta,
                  const float* __restrict__ stats, const int* __restrict__ batch,
                  float* __restrict__ zbuf, const int l, ushort_t* __restrict__ Xh)
{
    __shared__ float sscale[DF], sshift[DF];
    __shared__ float zslab[4][DF];
    __shared__ int sg0;
    const int tid = threadIdx.x;
    const int lane = tid & 63;
    const int wave = tid >> 6;
    const int brow0 = blockIdx.x * 128;
    const int row0 = brow0 + wave * 32;
    const int rA0 = row0 + (lane & 15);
    const int rAc0 = (rA0 < NN) ? rA0 : (NN - 1);
    const int rA1 = rA0 + 16;
    const int rAc1 = (rA1 < NN) ? rA1 : (NN - 1);
    const int kg = lane >> 4;

    if (tid < DF) {
        float s = stats[tid], q = stats[DF + tid];
        float mu = s * (1.f / NN);
        float var = q * (1.f / NN) - mu * mu;
        float sc = gamma[tid] * rsqrtf(var + BN_EPS);
        sscale[tid] = sc;
        sshift[tid] = beta[tid] - mu * sc;
    }
    if (tid == 0) sg0 = batch[brow0];
    for (int t = tid; t < 4 * DF; t += 256) (&zslab[0][0])[t] = 0.f;
    __syncthreads();

    f32x4 acc0[8], acc1[8];
#pragma unroll
    for (int f = 0; f < 8; ++f) {
        acc0[f] = (f32x4){0.f, 0.f, 0.f, 0.f};
        acc1[f] = (f32x4){0.f, 0.f, 0.f, 0.f};
    }

    for (int s = 0; s < 4; ++s) {
        const int ko = s * 32 + kg * 8;
        f32x4 sc0 = *(const f32x4*)&sscale[ko];
        f32x4 sc1 = *(const f32x4*)&sscale[ko + 4];
        f32x4 sh0 = *(const f32x4*)&sshift[ko];
        f32x4 sh1 = *(const f32x4*)&sshift[ko + 4];
        bf16x8 ah0, al0, ah1, al1;
        {
            const float* ap = Hm + (size_t)rAc0 * DF + ko;
            f32x4 a0 = *(const f32x4*)ap;
            f32x4 a1 = *(const f32x4*)(ap + 4);
#pragma unroll
            for (int j = 0; j < 4; ++j) {
                unsigned h, lo;
                float v0 = fmaxf(0.f, a0[j] * sc0[j] + sh0[j]);
                float v1 = fmaxf(0.f, a1[j] * sc1[j] + sh1[j]);
                bsplit(v0, h, lo); ah0[j] = h; al0[j] = lo;
                bsplit(v1, h, lo); ah0[4 + j] = h; al0[4 + j] = lo;
            }
        }
        {
            const float* ap = Hm + (size_t)rAc1 * DF + ko;
            f32x4 a0 = *(const f32x4*)ap;
            f32x4 a1 = *(const f32x4*)(ap + 4);
#pragma unroll
            for (int j = 0; j < 4; ++j) {
                unsigned h, lo;
                float v0 = fmaxf(0.f, a0[j] * sc0[j] + sh0[j]);
                float v1 = fmaxf(0.f, a1[j] * sc1[j] + sh1[j]);
                bsplit(v0, h, lo); ah1[j] = h; al1[j] = lo;
                bsplit(v1, h, lo); ah1[4 + j] = h; al1[4 + j] = lo;
            }
        }
#pragma unroll
        for (int f = 0; f < 8; ++f) {
            const size_t boff = ((size_t)(f * 4 + s) * 64 + lane) * 8;
            bf16x8 bh = *(const bf16x8*)(Bh + boff);
            bf16x8 bl = *(const bf16x8*)(Bl + boff);
            acc0[f] = __builtin_amdgcn_mfma_f32_16x16x32_bf16(ah0, bh, acc0[f], 0, 0, 0);
            acc0[f] = __builtin_amdgcn_mfma_f32_16x16x32_bf16(al0, bh, acc0[f], 0, 0, 0);
            acc0[f] = __builtin_amdgcn_mfma_f32_16x16x32_bf16(ah0, bl, acc0[f], 0, 0, 0);
            acc1[f] = __builtin_amdgcn_mfma_f32_16x16x32_bf16(ah1, bh, acc1[f], 0, 0, 0);
            acc1[f] = __builtin_amdgcn_mfma_f32_16x16x32_bf16(al1, bh, acc1[f], 0, 0, 0);
            acc1[f] = __builtin_amdgcn_mfma_f32_16x16x32_bf16(ah1, bl, acc1[f], 0, 0, 0);
        }
    }

    const int colb = lane & 15;
    const int g0 = sg0;
#pragma unroll
    for (int rg = 0; rg < 2; ++rg) {
        const int rbase = row0 + rg * 16 + kg * 4;
        int g_[4]; bool val[4];
#pragma unroll
        for (int r = 0; r < 4; ++r) {
            int row = rbase + r;
            val[r] = row < NN;
            g_[r] = batch[val[r] ? row : (NN - 1)];
        }
        const bool uni = val[3] && (g_[0] == g_[3]);
#pragma unroll
        for (int f = 0; f < 8; ++f) {
            const int col = f * 16 + colb;
            const float bcol = bias[col];
            const f32x4 a = rg ? acc1[f] : acc0[f];
            float vv[4];
#pragma unroll
            for (int r = 0; r < 4; ++r) vv[r] = a[r] + bcol;
#pragma unroll
            for (int r = 0; r < 4; ++r)
                if (val[r]) Xh[(size_t)(rbase + r) * DF + col] = (ushort_t)rne16(vv[r]);
            if (uni) {
                float sum = (vv[0] + vv[1]) + (vv[2] + vv[3]);
                int idx = g_[0] - g0;
                if ((unsigned)idx < 4u) atomicAdd(&zslab[idx][col], sum);
                else atomicAdd(&zbuf[(size_t)g_[0] * (NL * DF) + l * DF + col], sum);
            } else {
#pragma unroll
                for (int r = 0; r < 4; ++r) if (val[r]) {
                    int idx = g_[r] - g0;
                    if ((unsigned)idx < 4u) atomicAdd(&zslab[idx][col], vv[r]);
                    else atomicAdd(&zbuf[(size_t)g_[r] * (NL * DF) + l * DF + col], vv[r]);
                }
            }
        }
    }
    __syncthreads();
    int lastrow = brow0 + 127; if (lastrow >= NN) lastrow = NN - 1;
    int ns = batch[lastrow] - g0 + 1; if (ns > 4) ns = 4;
    if (tid < DF)
        for (int sl = 0; sl < ns; ++sl)
            atomicAdd(&zbuf[(size_t)(g0 + sl) * (NL * DF) + l * DF + tid], zslab[sl][tid]);
}

// ---------------------------------------------------------------- final MLP
__global__ __launch_bounds__(128)
void p1_kernel(const float* __restrict__ z, const float* __restrict__ Wp1,
               const float* __restrict__ bp1, float* __restrict__ z1)
{
    const int g = blockIdx.x;
    const int f = threadIdx.x;
    const float* zr = z + (size_t)g * (NL * DF);
    float a0 = 0.f, a1 = 0.f, a2 = 0.f, a3 = 0.f;
#pragma unroll 4
    for (int k = 0; k < NL * DF; k += 4) {
        float4 zv = ld4(zr + k);
        a0 = fmaf(zv.x, Wp1[(size_t)(k + 0) * DF + f], a0);
        a1 = fmaf(zv.y, Wp1[(size_t)(k + 1) * DF + f], a1);
        a2 = fmaf(zv.z, Wp1[(size_t)(k + 2) * DF + f], a2);
        a3 = fmaf(zv.w, Wp1[(size_t)(k + 3) * DF + f], a3);
    }
    z1[(size_t)g * DF + f] = (a0 + a1) + (a2 + a3) + bp1[f];
}

__global__ __launch_bounds__(128)
void pbn_kernel(const float* __restrict__ z1, const float* __restrict__ gp,
                const float* __restrict__ bp, float* __restrict__ pstats)
{
    const int f = threadIdx.x;
    float s = 0.f, q = 0.f;
#pragma unroll 8
    for (int g = 0; g < NG; ++g) {
        float v = z1[(size_t)g * DF + f];
        s += v; q += v * v;
    }
    float mu = s * (1.f / NG);
    float var = q * (1.f / NG) - mu * mu;
    float sc = gp[f] * rsqrtf(var + BN_EPS);
    pstats[f] = sc;
    pstats[DF + f] = bp[f] - mu * sc;
}

__global__ __launch_bounds__(128)
void p3_kernel(const float* __restrict__ z1, const float* __restrict__ pstats,
               const float* __restrict__ Wp2, const float* __restrict__ bp2,
               float* __restrict__ out)
{
    __shared__ float a[DF];
    const int g = blockIdx.x;
    const int f = threadIdx.x;
    float v = z1[(size_t)g * DF + f];
    a[f] = fmaxf(0.f, v * pstats[f] + pstats[DF + f]);
    __syncthreads();
    if (f < NOUTC) {
        float acc = bp2[f];
        for (int k = 0; k < DF; ++k)
            acc = fmaf(a[k], Wp2[k * NOUTC + f], acc);
        out[(size_t)g * NOUTC + f] = acc;
    }
}

// ---------------------------------------------------------------- launch
extern "C" void kernel_launch(void* const* d_in, const int* in_sizes, int n_in,
                              void* d_out, int out_size, void* d_ws, size_t ws_size,
                              hipStream_t stream)
{
    const float* d_x   = (const float*)d_in[0];
    const int*   d_ei  = (const int*)d_in[1];
    const int*   d_bat = (const int*)d_in[2];
    const float* d_W1  = (const float*)d_in[4];
    const float* d_b1  = (const float*)d_in[5];
    const float* d_gm  = (const float*)d_in[6];
    const float* d_bt  = (const float*)d_in[7];
    const float* d_W2  = (const float*)d_in[8];
    const float* d_b2  = (const float*)d_in[9];
    const float* d_Wp1 = (const float*)d_in[10];
    const float* d_bp1 = (const float*)d_in[11];
    const float* d_gp  = (const float*)d_in[12];
    const float* d_bp  = (const float*)d_in[13];
    const float* d_Wp2 = (const float*)d_in[14];
    const float* d_bp2 = (const float*)d_in[15];
    float* out = (float*)d_out;

    char* ws = (char*)d_ws;
    // ---- zero region (one memset): zbuf | rowptr | fill | stats4
    float*    zbuf    = (float*)(ws + 0);          // 256*512 f32 = 524288 B
    int*      rowptr  = (int*)(ws + 524288);       // (NN+1) ints = 200004 B
    int*      fill    = (int*)(ws + 724292);       // NN ints = 200000 B
    float*    stats4  = (float*)(ws + 924292);     // 4 layers * 256 f32 = 4096 B
    const size_t zero_len = 928388;
    // ---- rest
    int*      colidx  = (int*)(ws + 928640);       // NE ints
    int*      blksums = (int*)(ws + 4128640);      // 64 ints
    int*      gstart  = (int*)(ws + 4128896);      // NG+1 ints
    float*    pstats  = (float*)(ws + 4130048);    // 256 f32
    float*    z1buf   = (float*)(ws + 4131072);    // NG*128 f32
    ushort_t* Whi     = (ushort_t*)(ws + 4262144); // 8*16384 bf16
    ushort_t* Wlo     = (ushort_t*)(ws + 4524288);
    ushort_t* xh      = (ushort_t*)(ws + 4786432); // NN*128 bf16
    ushort_t* th      = (ushort_t*)(ws + 17586432);
    ushort_t* tl      = (ushort_t*)(ws + 30386432);
    float*    hbuf    = (float*)(ws + 43186432);   // NN*128 f32 (ends 68786432)

    hipMemsetAsync(ws, 0, zero_len, stream);

    count_kernel<<<(NE + 255) / 256, 256, 0, stream>>>(d_ei, rowptr);
    scan1_kernel<<<49, 256, 0, stream>>>(rowptr, blksums);
    scan2_kernel<<<1, 64, 0, stream>>>(blksums, 49);
    scan3_kernel<<<(NN + 255) / 256, 256, 0, stream>>>(rowptr, blksums);
    scatter_kernel<<<(NE + 255) / 256, 256, 0, stream>>>(d_ei, rowptr, fill, colidx);
    gstart_kernel<<<2, 256, 0, stream>>>(d_bat, gstart);
    wprep_kernel<<<256, 64, 0, stream>>>(d_W1, d_W2, Whi, Wlo);
    xtob16_kernel<<<NN * DF / 1024, 256, 0, stream>>>(d_x, xh);

    const int gemm_grid = (NN + 127) / 128;   // 391
    for (int l = 0; l < NL; ++l) {
        spmm_kernel<<<(NN + 3) / 4, 256, 0, stream>>>(xh, rowptr, colidx, th, tl);
        gemm1_kernel<<<gemm_grid, 256, 0, stream>>>(th, tl,
                                                    Whi + (size_t)l * DF * DF,
                                                    Wlo + (size_t)l * DF * DF,
                                                    d_b1 + l * DF, hbuf,
                                                    stats4 + l * 256);
        gemm2_kernel<<<gemm_grid, 256, 0, stream>>>(hbuf,
                                                    Whi + (size_t)(4 + l) * DF * DF,
                                                    Wlo + (size_t)(4 + l) * DF * DF,
                                                    d_b2 + l * DF, d_gm + l * DF,
                                                    d_bt + l * DF, stats4 + l * 256,
                                                    d_bat, zbuf, l, xh);
    }
    p1_kernel<<<NG, 128, 0, stream>>>(zbuf, d_Wp1, d_bp1, z1buf);
    pbn_kernel<<<1, 128, 0, stream>>>(z1buf, d_gp, d_bp, pstats);
    p3_kernel<<<NG, 128, 0, stream>>>(z1buf, pstats, d_Wp2, d_bp2, out);
}

// Round 10
// 575.365 us; speedup vs baseline: 1.9758x; 1.0262x over previous
//
#include <hip/hip_runtime.h>

#define NN 50000
#define NE 800000
#define DF 128
#define NG 256
#define NL 4
#define NOUTC 10
#define BN_EPS 1e-5f

typedef __attribute__((ext_vector_type(8))) short bf16x8;
typedef __attribute__((ext_vector_type(4))) float f32x4;
typedef unsigned short ushort_t;

static __device__ __forceinline__ float4 ld4(const float* p) { return *(const float4*)p; }

// RNE f32 -> bf16 bits
static __device__ __forceinline__ unsigned rne16(float x)
{
    unsigned u = __float_as_uint(x);
    return (u + 0x7fffu + ((u >> 16) & 1u)) >> 16;
}
// split f32 into hi (RNE bf16) + lo (RNE bf16 of remainder); hi+lo ~ exact
static __device__ __forceinline__ void bsplit(float x, unsigned& h, unsigned& l)
{
    h = rne16(x);
    float rest = x - __uint_as_float(h << 16);
    l = rne16(rest);
}

// ---------------------------------------------------------------- CSR build (counts in-place in rowptr)
__global__ void count_kernel(const int* __restrict__ ei, int* __restrict__ rowptr)
{
    int e = blockIdx.x * blockDim.x + threadIdx.x;
    if (e < NE) atomicAdd(&rowptr[ei[NE + e]], 1);   // dst = ei[1][e]
}

__global__ void scan1_kernel(int* __restrict__ rp, int* __restrict__ blksums)
{
    __shared__ int sdata[256];
    const int tid = threadIdx.x;
    const int base = blockIdx.x * 1024;
    int v[4]; int s = 0;
#pragma unroll
    for (int p = 0; p < 4; ++p) {
        int idx = base + tid * 4 + p;
        v[p] = (idx < NN) ? rp[idx] : 0;
        s += v[p];
    }
    sdata[tid] = s;
    __syncthreads();
    for (int off = 1; off < 256; off <<= 1) {
        int t = (tid >= off) ? sdata[tid - off] : 0;
        __syncthreads();
        if (tid >= off) sdata[tid] += t;
        __syncthreads();
    }
    int run = (tid == 0) ? 0 : sdata[tid - 1];
#pragma unroll
    for (int p = 0; p < 4; ++p) {
        int idx = base + tid * 4 + p;
        if (idx < NN) rp[idx] = run;
        run += v[p];
    }
    if (tid == 255) blksums[blockIdx.x] = sdata[255];
}

// scan3 with in-block prefix of the 49 block sums (scan2 folded in)
__global__ void scan3_kernel(int* __restrict__ rowptr, const int* __restrict__ blksums)
{
    __shared__ int sb[49];
    __shared__ int soff;
    const int t = threadIdx.x, b = blockIdx.x;
    if (t < 49) sb[t] = blksums[t];
    __syncthreads();
    if (t == 0) {
        int p = b >> 2, run = 0;
        for (int i = 0; i < p; ++i) run += sb[i];
        soff = run;
    }
    __syncthreads();
    int idx = b * 256 + t;
    if (idx < NN) rowptr[idx] += soff;
    if (idx == 0) rowptr[NN] = NE;
}

__global__ void scatter_kernel(const int* __restrict__ ei, const int* __restrict__ rowptr,
                               int* __restrict__ fill, int* __restrict__ colidx)
{
    int e = blockIdx.x * blockDim.x + threadIdx.x;
    if (e < NE) {
        int d = ei[NE + e];
        int s = ei[e];
        int p = atomicAdd(&fill[d], 1);
        colidx[rowptr[d] + p] = s;
    }
}

// ---------------------------------------------------------------- prep: x->bf16 + W->fragment blobs
// blob[m][nblk(8)][s(4)][lane(64)][j(8)], element = W[k][n], k=s*32+(lane>>4)*8+j, n=nblk*16+(lane&15)
__global__ __launch_bounds__(256)
void prep_kernel(const float* __restrict__ x, const float* __restrict__ W1,
                 const float* __restrict__ W2, ushort_t* __restrict__ xh,
                 ushort_t* __restrict__ Bh, ushort_t* __restrict__ Bl)
{
    const int b = blockIdx.x, t = threadIdx.x;
    // x -> bf16 (6250 blocks * 256 thr * 4 f32 = NN*DF exactly)
    size_t idx = ((size_t)b * 256 + t) * 4;
    float4 v = ld4(x + idx);
    unsigned p0 = rne16(v.x) | (rne16(v.y) << 16);
    unsigned p1 = rne16(v.z) | (rne16(v.w) << 16);
    uint2 pv; pv.x = p0; pv.y = p1;
    *(uint2*)(xh + idx) = pv;
    // W prep on blocks 0..255, threads 0..63
    if (b < 256 && t < 64) {
        const int m = b >> 5;
        const int nblk = (b >> 2) & 7;
        const int s = b & 3;
        const float* Wsrc = (m < 4) ? (W1 + (size_t)m * DF * DF)
                                    : (W2 + (size_t)(m - 4) * DF * DF);
        const int n = nblk * 16 + (t & 15);
        const int k0 = s * 32 + (t >> 4) * 8;
        size_t off = (size_t)m * (DF * DF) + ((size_t)(nblk * 4 + s) * 64 + t) * 8;
#pragma unroll
        for (int j = 0; j < 8; ++j) {
            float w = Wsrc[(size_t)(k0 + j) * DF + n];
            unsigned h, lo;
            bsplit(w, h, lo);
            Bh[off + j] = (ushort_t)h;
            Bl[off + j] = (ushort_t)lo;
        }
    }
}

// ---------------------------------------------------------------- SpMM: t = x + A@x (bf16 gather, f32 acc, hi/lo out)
template<int K>
static __device__ __forceinline__ void gatherK(const ushort_t* __restrict__ xh,
                                               const int* __restrict__ colidx,
                                               int e, int c2, float& ax, float& ay)
{
    unsigned v[K];
#pragma unroll
    for (int k = 0; k < K; ++k) {
        int j = colidx[e + k];
        v[k] = *(const unsigned*)(xh + (size_t)j * DF + c2);
    }
#pragma unroll
    for (int k = 0; k < K; ++k) {
        ax += __uint_as_float(v[k] << 16);
        ay += __uint_as_float(v[k] & 0xffff0000u);
    }
}

__global__ __launch_bounds__(256)
void spmm_kernel(const ushort_t* __restrict__ xh, const int* __restrict__ rowptr,
                 const int* __restrict__ colidx, ushort_t* __restrict__ th,
                 ushort_t* __restrict__ tl)
{
    const int lane = threadIdx.x & 63;
    const int i = __builtin_amdgcn_readfirstlane(blockIdx.x * 4 + (threadIdx.x >> 6));
    const int c2 = lane * 2;
    unsigned sv = *(const unsigned*)(xh + (size_t)i * DF + c2);
    float ax = __uint_as_float(sv << 16);
    float ay = __uint_as_float(sv & 0xffff0000u);
    int e = rowptr[i];
    const int e1 = rowptr[i + 1];
    for (; e + 16 <= e1; e += 16) gatherK<16>(xh, colidx, e, c2, ax, ay);
    if (e1 - e >= 8) { gatherK<8>(xh, colidx, e, c2, ax, ay); e += 8; }
    if (e1 - e >= 4) { gatherK<4>(xh, colidx, e, c2, ax, ay); e += 4; }
    if (e1 - e >= 2) { gatherK<2>(xh, colidx, e, c2, ax, ay); e += 2; }
    if (e1 - e >= 1) { gatherK<1>(xh, colidx, e, c2, ax, ay); }
    unsigned h0, l0, h1, l1;
    bsplit(ax, h0, l0);
    bsplit(ay, h1, l1);
    *(unsigned*)(th + (size_t)i * DF + c2) = h0 | (h1 << 16);
    *(unsigned*)(tl + (size_t)i * DF + c2) = l0 | (l1 << 16);
}

// ---------------------------------------------------------------- GEMM1: h = t@W1 + b1, fused BN stats
// 32 rows/wave (2 row-groups), A-frags direct from th/tl, 3-MFMA split precision
__global__ __launch_bounds__(256)
void gemm1_kernel(const ushort_t* __restrict__ th, const ushort_t* __restrict__ tl,
                  const ushort_t* __restrict__ Bh, const ushort_t* __restrict__ Bl,
                  const float* __restrict__ bias, float* __restrict__ C,
                  float* __restrict__ stats)
{
    __shared__ float red[2][DF];
    const int tid = threadIdx.x;
    const int lane = tid & 63;
    const int wave = tid >> 6;
    const int row0 = blockIdx.x * 128 + wave * 32;
    const int rA0 = row0 + (lane & 15);
    const int rAc0 = (rA0 < NN) ? rA0 : (NN - 1);
    const int rA1 = rA0 + 16;
    const int rAc1 = (rA1 < NN) ? rA1 : (NN - 1);
    const int kg = lane >> 4;

    if (tid < DF) { red[0][tid] = 0.f; red[1][tid] = 0.f; }
    __syncthreads();

    f32x4 acc0[8], acc1[8];
#pragma unroll
    for (int f = 0; f < 8; ++f) {
        acc0[f] = (f32x4){0.f, 0.f, 0.f, 0.f};
        acc1[f] = (f32x4){0.f, 0.f, 0.f, 0.f};
    }

    for (int s = 0; s < 4; ++s) {
        const int ko = s * 32 + kg * 8;
        bf16x8 ah0 = *(const bf16x8*)(th + (size_t)rAc0 * DF + ko);
        bf16x8 al0 = *(const bf16x8*)(tl + (size_t)rAc0 * DF + ko);
        bf16x8 ah1 = *(const bf16x8*)(th + (size_t)rAc1 * DF + ko);
        bf16x8 al1 = *(const bf16x8*)(tl + (size_t)rAc1 * DF + ko);
#pragma unroll
        for (int f = 0; f < 8; ++f) {
            const size_t boff = ((size_t)(f * 4 + s) * 64 + lane) * 8;
            bf16x8 bh = *(const bf16x8*)(Bh + boff);
            bf16x8 bl = *(const bf16x8*)(Bl + boff);
            acc0[f] = __builtin_amdgcn_mfma_f32_16x16x32_bf16(ah0, bh, acc0[f], 0, 0, 0);
            acc0[f] = __builtin_amdgcn_mfma_f32_16x16x32_bf16(al0, bh, acc0[f], 0, 0, 0);
            acc0[f] = __builtin_amdgcn_mfma_f32_16x16x32_bf16(ah0, bl, acc0[f], 0, 0, 0);
            acc1[f] = __builtin_amdgcn_mfma_f32_16x16x32_bf16(ah1, bh, acc1[f], 0, 0, 0);
            acc1[f] = __builtin_amdgcn_mfma_f32_16x16x32_bf16(al1, bh, acc1[f], 0, 0, 0);
            acc1[f] = __builtin_amdgcn_mfma_f32_16x16x32_bf16(ah1, bl, acc1[f], 0, 0, 0);
        }
    }

    const int colb = lane & 15;
    const int rb0 = row0 + kg * 4;
    const int rb1 = row0 + 16 + kg * 4;
#pragma unroll
    for (int f = 0; f < 8; ++f) {
        const int col = f * 16 + colb;
        const float bcol = bias[col];
        float sj = 0.f, qj = 0.f;
#pragma unroll
        for (int r = 0; r < 4; ++r) {
            int row = rb0 + r;
            if (row < NN) {
                float v = acc0[f][r] + bcol;
                C[(size_t)row * DF + col] = v;
                sj += v; qj += v * v;
            }
        }
#pragma unroll
        for (int r = 0; r < 4; ++r) {
            int row = rb1 + r;
            if (row < NN) {
                float v = acc1[f][r] + bcol;
                C[(size_t)row * DF + col] = v;
                sj += v; qj += v * v;
            }
        }
        atomicAdd(&red[0][col], sj);
        atomicAdd(&red[1][col], qj);
    }
    __syncthreads();
    if (tid < DF) {
        atomicAdd(&stats[tid], red[0][tid]);
        atomicAdd(&stats[DF + tid], red[1][tid]);
    }
}

// ---------------------------------------------------------------- GEMM2: x' = relu(bn(h))@W2 + b2, fused pool, bf16 out
__global__ __launch_bounds__(256)
void gemm2_kernel(const float* __restrict__ Hm, const ushort_t* __restrict__ Bh,
                  const ushort_t* __restrict__ Bl, const float* __restrict__ bias,
                  const float* __restrict__ gamma, const float* __restrict__ beta,
                  const float* __restrict__ stats, const int* __restrict__ batch,
                  float* __restrict__ zbuf, const int l, ushort_t* __restrict__ Xh)
{
    __shared__ float sscale[DF], sshift[DF];
    __shared__ float zslab[4][DF];
    __shared__ int sg0;
    const int tid = threadIdx.x;
    const int lane = tid & 63;
    const int wave = tid >> 6;
    const int brow0 = blockIdx.x * 128;
    const int row0 = brow0 + wave * 32;
    const int rA0 = row0 + (lane & 15);
    const int rAc0 = (rA0 < NN) ? rA0 : (NN - 1);
    const int rA1 = rA0 + 16;
    const int rAc1 = (rA1 < NN) ? rA1 : (NN - 1);
    const int kg = lane >> 4;

    if (tid < DF) {
        float s = stats[tid], q = stats[DF + tid];
        float mu = s * (1.f / NN);
        float var = q * (1.f / NN) - mu * mu;
        float sc = gamma[tid] * rsqrtf(var + BN_EPS);
        sscale[tid] = sc;
        sshift[tid] = beta[tid] - mu * sc;
    }
    if (tid == 0) sg0 = batch[brow0];
    for (int t = tid; t < 4 * DF; t += 256) (&zslab[0][0])[t] = 0.f;
    __syncthreads();

    f32x4 acc0[8], acc1[8];
#pragma unroll
    for (int f = 0; f < 8; ++f) {
        acc0[f] = (f32x4){0.f, 0.f, 0.f, 0.f};
        acc1[f] = (f32x4){0.f, 0.f, 0.f, 0.f};
    }

    for (int s = 0; s < 4; ++s) {
        const int ko = s * 32 + kg * 8;
        f32x4 sc0 = *(const f32x4*)&sscale[ko];
        f32x4 sc1 = *(const f32x4*)&sscale[ko + 4];
        f32x4 sh0 = *(const f32x4*)&sshift[ko];
        f32x4 sh1 = *(const f32x4*)&sshift[ko + 4];
        bf16x8 ah0, al0, ah1, al1;
        {
            const float* ap = Hm + (size_t)rAc0 * DF + ko;
            f32x4 a0 = *(const f32x4*)ap;
            f32x4 a1 = *(const f32x4*)(ap + 4);
#pragma unroll
            for (int j = 0; j < 4; ++j) {
                unsigned h, lo;
                float v0 = fmaxf(0.f, a0[j] * sc0[j] + sh0[j]);
                float v1 = fmaxf(0.f, a1[j] * sc1[j] + sh1[j]);
                bsplit(v0, h, lo); ah0[j] = h; al0[j] = lo;
                bsplit(v1, h, lo); ah0[4 + j] = h; al0[4 + j] = lo;
            }
        }
        {
            const float* ap = Hm + (size_t)rAc1 * DF + ko;
            f32x4 a0 = *(const f32x4*)ap;
            f32x4 a1 = *(const f32x4*)(ap + 4);
#pragma unroll
            for (int j = 0; j < 4; ++j) {
                unsigned h, lo;
                float v0 = fmaxf(0.f, a0[j] * sc0[j] + sh0[j]);
                float v1 = fmaxf(0.f, a1[j] * sc1[j] + sh1[j]);
                bsplit(v0, h, lo); ah1[j] = h; al1[j] = lo;
                bsplit(v1, h, lo); ah1[4 + j] = h; al1[4 + j] = lo;
            }
        }
#pragma unroll
        for (int f = 0; f < 8; ++f) {
            const size_t boff = ((size_t)(f * 4 + s) * 64 + lane) * 8;
            bf16x8 bh = *(const bf16x8*)(Bh + boff);
            bf16x8 bl = *(const bf16x8*)(Bl + boff);
            acc0[f] = __builtin_amdgcn_mfma_f32_16x16x32_bf16(ah0, bh, acc0[f], 0, 0, 0);
            acc0[f] = __builtin_amdgcn_mfma_f32_16x16x32_bf16(al0, bh, acc0[f], 0, 0, 0);
            acc0[f] = __builtin_amdgcn_mfma_f32_16x16x32_bf16(ah0, bl, acc0[f], 0, 0, 0);
            acc1[f] = __builtin_amdgcn_mfma_f32_16x16x32_bf16(ah1, bh, acc1[f], 0, 0, 0);
            acc1[f] = __builtin_amdgcn_mfma_f32_16x16x32_bf16(al1, bh, acc1[f], 0, 0, 0);
            acc1[f] = __builtin_amdgcn_mfma_f32_16x16x32_bf16(ah1, bl, acc1[f], 0, 0, 0);
        }
    }

    const int colb = lane & 15;
    const int g0 = sg0;
#pragma unroll
    for (int rg = 0; rg < 2; ++rg) {
        const int rbase = row0 + rg * 16 + kg * 4;
        int g_[4]; bool val[4];
#pragma unroll
        for (int r = 0; r < 4; ++r) {
            int row = rbase + r;
            val[r] = row < NN;
            g_[r] = batch[val[r] ? row : (NN - 1)];
        }
        const bool uni = val[3] && (g_[0] == g_[3]);
#pragma unroll
        for (int f = 0; f < 8; ++f) {
            const int col = f * 16 + colb;
            const float bcol = bias[col];
            const f32x4 a = rg ? acc1[f] : acc0[f];
            float vv[4];
#pragma unroll
            for (int r = 0; r < 4; ++r) vv[r] = a[r] + bcol;
#pragma unroll
            for (int r = 0; r < 4; ++r)
                if (val[r]) Xh[(size_t)(rbase + r) * DF + col] = (ushort_t)rne16(vv[r]);
            if (uni) {
                float sum = (vv[0] + vv[1]) + (vv[2] + vv[3]);
                int idx = g_[0] - g0;
                if ((unsigned)idx < 4u) atomicAdd(&zslab[idx][col], sum);
                else atomicAdd(&zbuf[(size_t)g_[0] * (NL * DF) + l * DF + col], sum);
            } else {
#pragma unroll
                for (int r = 0; r < 4; ++r) if (val[r]) {
                    int idx = g_[r] - g0;
                    if ((unsigned)idx < 4u) atomicAdd(&zslab[idx][col], vv[r]);
                    else atomicAdd(&zbuf[(size_t)g_[r] * (NL * DF) + l * DF + col], vv[r]);
                }
            }
        }
    }
    __syncthreads();
    int lastrow = brow0 + 127; if (lastrow >= NN) lastrow = NN - 1;
    int ns = batch[lastrow] - g0 + 1; if (ns > 4) ns = 4;
    if (tid < DF)
        for (int sl = 0; sl < ns; ++sl)
            atomicAdd(&zbuf[(size_t)(g0 + sl) * (NL * DF) + l * DF + tid], zslab[sl][tid]);
}

// ---------------------------------------------------------------- final MLP
__global__ __launch_bounds__(128)
void p1_kernel(const float* __restrict__ z, const float* __restrict__ Wp1,
               const float* __restrict__ bp1, float* __restrict__ z1)
{
    const int g = blockIdx.x;
    const int f = threadIdx.x;
    const float* zr = z + (size_t)g * (NL * DF);
    float a0 = 0.f, a1 = 0.f, a2 = 0.f, a3 = 0.f;
#pragma unroll 4
    for (int k = 0; k < NL * DF; k += 4) {
        float4 zv = ld4(zr + k);
        a0 = fmaf(zv.x, Wp1[(size_t)(k + 0) * DF + f], a0);
        a1 = fmaf(zv.y, Wp1[(size_t)(k + 1) * DF + f], a1);
        a2 = fmaf(zv.z, Wp1[(size_t)(k + 2) * DF + f], a2);
        a3 = fmaf(zv.w, Wp1[(size_t)(k + 3) * DF + f], a3);
    }
    z1[(size_t)g * DF + f] = (a0 + a1) + (a2 + a3) + bp1[f];
}

// pbn fused into p3: every block recomputes the 128-col stats (z1 is L2-hot)
__global__ __launch_bounds__(128)
void p23_kernel(const float* __restrict__ z1, const float* __restrict__ gp,
                const float* __restrict__ bp, const float* __restrict__ Wp2,
                const float* __restrict__ bp2, float* __restrict__ out)
{
    __shared__ float a[DF];
    const int g = blockIdx.x;
    const int f = threadIdx.x;
    float s = 0.f, q = 0.f;
#pragma unroll 8
    for (int r = 0; r < NG; ++r) {
        float v = z1[(size_t)r * DF + f];
        s += v; q += v * v;
    }
    float mu = s * (1.f / NG);
    float var = q * (1.f / NG) - mu * mu;
    float sc = gp[f] * rsqrtf(var + BN_EPS);
    float sh = bp[f] - mu * sc;
    float v = z1[(size_t)g * DF + f];
    a[f] = fmaxf(0.f, v * sc + sh);
    __syncthreads();
    if (f < NOUTC) {
        float acc = bp2[f];
        for (int k = 0; k < DF; ++k)
            acc = fmaf(a[k], Wp2[k * NOUTC + f], acc);
        out[(size_t)g * NOUTC + f] = acc;
    }
}

// ---------------------------------------------------------------- launch
extern "C" void kernel_launch(void* const* d_in, const int* in_sizes, int n_in,
                              void* d_out, int out_size, void* d_ws, size_t ws_size,
                              hipStream_t stream)
{
    const float* d_x   = (const float*)d_in[0];
    const int*   d_ei  = (const int*)d_in[1];
    const int*   d_bat = (const int*)d_in[2];
    const float* d_W1  = (const float*)d_in[4];
    const float* d_b1  = (const float*)d_in[5];
    const float* d_gm  = (const float*)d_in[6];
    const float* d_bt  = (const float*)d_in[7];
    const float* d_W2  = (const float*)d_in[8];
    const float* d_b2  = (const float*)d_in[9];
    const float* d_Wp1 = (const float*)d_in[10];
    const float* d_bp1 = (const float*)d_in[11];
    const float* d_gp  = (const float*)d_in[12];
    const float* d_bp  = (const float*)d_in[13];
    const float* d_Wp2 = (const float*)d_in[14];
    const float* d_bp2 = (const float*)d_in[15];
    float* out = (float*)d_out;

    char* ws = (char*)d_ws;
    // ---- zero region (one memset): zbuf | rowptr | fill | stats4
    float*    zbuf    = (float*)(ws + 0);          // 256*512 f32 = 524288 B
    int*      rowptr  = (int*)(ws + 524288);       // (NN+1) ints
    int*      fill    = (int*)(ws + 724292);       // NN ints
    float*    stats4  = (float*)(ws + 924292);     // 4*256 f32
    const size_t zero_len = 928388;
    // ---- rest
    int*      colidx  = (int*)(ws + 928640);       // NE ints (ends 4128640)
    int*      blksums = (int*)(ws + 4128640);      // 64 ints
    float*    z1buf   = (float*)(ws + 4130048);    // NG*128 f32 (ends 4261120)
    ushort_t* Whi     = (ushort_t*)(ws + 4261120); // 8*16384 bf16 (ends 4523264)
    ushort_t* Wlo     = (ushort_t*)(ws + 4523264); // (ends 4785408)
    ushort_t* xh      = (ushort_t*)(ws + 4785408); // NN*128 bf16 (ends 17585408)
    ushort_t* th      = (ushort_t*)(ws + 17585408);// (ends 30385408)
    ushort_t* tl      = (ushort_t*)(ws + 30385408);// (ends 43185408)
    float*    hbuf    = (float*)(ws + 43185408);   // NN*128 f32 (ends 68785408)

    hipMemsetAsync(ws, 0, zero_len, stream);

    count_kernel<<<(NE + 255) / 256, 256, 0, stream>>>(d_ei, rowptr);
    scan1_kernel<<<49, 256, 0, stream>>>(rowptr, blksums);
    scan3_kernel<<<(NN + 255) / 256, 256, 0, stream>>>(rowptr, blksums);
    scatter_kernel<<<(NE + 255) / 256, 256, 0, stream>>>(d_ei, rowptr, fill, colidx);
    prep_kernel<<<NN * DF / 1024, 256, 0, stream>>>(d_x, d_W1, d_W2, xh, Whi, Wlo);

    const int gemm_grid = (NN + 127) / 128;   // 391
    for (int l = 0; l < NL; ++l) {
        spmm_kernel<<<(NN + 3) / 4, 256, 0, stream>>>(xh, rowptr, colidx, th, tl);
        gemm1_kernel<<<gemm_grid, 256, 0, stream>>>(th, tl,
                                                    Whi + (size_t)l * DF * DF,
                                                    Wlo + (size_t)l * DF * DF,
                                                    d_b1 + l * DF, hbuf,
                                                    stats4 + l * 256);
        gemm2_kernel<<<gemm_grid, 256, 0, stream>>>(hbuf,
                                                    Whi + (size_t)(4 + l) * DF * DF,
                                                    Wlo + (size_t)(4 + l) * DF * DF,
                                                    d_b2 + l * DF, d_gm + l * DF,
                                                    d_bt + l * DF, stats4 + l * 256,
                                                    d_bat, zbuf, l, xh);
    }
    p1_kernel<<<NG, 128, 0, stream>>>(zbuf, d_Wp1, d_bp1, z1buf);
    p23_kernel<<<NG, 128, 0, stream>>>(z1buf, d_gp, d_bp, d_Wp2, d_bp2, out);
}

// Round 13
// 546.703 us; speedup vs baseline: 2.0794x; 1.0524x over previous
//
#include <hip/hip_runtime.h>

#define NN 50000
#define NE 800000
#define DF 128
#define NG 256
#define NL 4
#define NOUTC 10
#define BN_EPS 1e-5f

typedef __attribute__((ext_vector_type(8))) short bf16x8;
typedef __attribute__((ext_vector_type(4))) float f32x4;
typedef unsigned short ushort_t;

static __device__ __forceinline__ float4 ld4(const float* p) { return *(const float4*)p; }

// RNE f32 -> bf16 bits
static __device__ __forceinline__ unsigned rne16(float x)
{
    unsigned u = __float_as_uint(x);
    return (u + 0x7fffu + ((u >> 16) & 1u)) >> 16;
}
// split f32 into hi (RNE bf16) + lo (RNE bf16 of remainder); hi+lo ~ exact
static __device__ __forceinline__ void bsplit(float x, unsigned& h, unsigned& l)
{
    h = rne16(x);
    float rest = x - __uint_as_float(h << 16);
    l = rne16(rest);
}

// ---------------------------------------------------------------- CSR build
// count + rank: rank[e] = position of edge e within its dst row (atomic return value)
__global__ __launch_bounds__(256)
void count_kernel(const int* __restrict__ ei, int* __restrict__ rowptr,
                  int* __restrict__ rank)
{
    int e0 = (blockIdx.x * 256 + threadIdx.x) * 4;
    if (e0 + 4 <= NE) {
        int4 d = *(const int4*)(ei + NE + e0);
        int4 r;
        r.x = atomicAdd(&rowptr[d.x], 1);
        r.y = atomicAdd(&rowptr[d.y], 1);
        r.z = atomicAdd(&rowptr[d.z], 1);
        r.w = atomicAdd(&rowptr[d.w], 1);
        *(int4*)(rank + e0) = r;
    } else {
        for (int e = e0; e < NE; ++e)
            rank[e] = atomicAdd(&rowptr[ei[NE + e]], 1);
    }
}

__global__ void scan1_kernel(int* __restrict__ rp, int* __restrict__ blksums)
{
    __shared__ int sdata[256];
    const int tid = threadIdx.x;
    const int base = blockIdx.x * 1024;
    int v[4]; int s = 0;
#pragma unroll
    for (int p = 0; p < 4; ++p) {
        int idx = base + tid * 4 + p;
        v[p] = (idx < NN) ? rp[idx] : 0;
        s += v[p];
    }
    sdata[tid] = s;
    __syncthreads();
    for (int off = 1; off < 256; off <<= 1) {
        int t = (tid >= off) ? sdata[tid - off] : 0;
        __syncthreads();
        if (tid >= off) sdata[tid] += t;
        __syncthreads();
    }
    int run = (tid == 0) ? 0 : sdata[tid - 1];
#pragma unroll
    for (int p = 0; p < 4; ++p) {
        int idx = base + tid * 4 + p;
        if (idx < NN) rp[idx] = run;
        run += v[p];
    }
    if (tid == 255) blksums[blockIdx.x] = sdata[255];
}

// scan3 with in-block prefix of the 49 block sums (scan2 folded in)
__global__ void scan3_kernel(int* __restrict__ rowptr, const int* __restrict__ blksums)
{
    __shared__ int sb[49];
    __shared__ int soff;
    const int t = threadIdx.x, b = blockIdx.x;
    if (t < 49) sb[t] = blksums[t];
    __syncthreads();
    if (t == 0) {
        int p = b >> 2, run = 0;
        for (int i = 0; i < p; ++i) run += sb[i];
        soff = run;
    }
    __syncthreads();
    int idx = b * 256 + t;
    if (idx < NN) rowptr[idx] += soff;
    if (idx == 0) rowptr[NN] = NE;
}

// scatter without atomics: uses precomputed rank
__global__ __launch_bounds__(256)
void scatter_kernel(const int* __restrict__ ei, const int* __restrict__ rowptr,
                    const int* __restrict__ rank, int* __restrict__ colidx)
{
    int e0 = (blockIdx.x * 256 + threadIdx.x) * 4;
    if (e0 + 4 <= NE) {
        int4 s = *(const int4*)(ei + e0);
        int4 d = *(const int4*)(ei + NE + e0);
        int4 r = *(const int4*)(rank + e0);
        colidx[rowptr[d.x] + r.x] = s.x;
        colidx[rowptr[d.y] + r.y] = s.y;
        colidx[rowptr[d.z] + r.z] = s.z;
        colidx[rowptr[d.w] + r.w] = s.w;
    } else {
        for (int e = e0; e < NE; ++e)
            colidx[rowptr[ei[NE + e]] + rank[e]] = ei[e];
    }
}

// ---------------------------------------------------------------- prep: x->bf16 + W->fragment blobs
// blob[m][nblk(8)][s(4)][lane(64)][j(8)], element = W[k][n], k=s*32+(lane>>4)*8+j, n=nblk*16+(lane&15)
__global__ __launch_bounds__(256)
void prep_kernel(const float* __restrict__ x, const float* __restrict__ W1,
                 const float* __restrict__ W2, ushort_t* __restrict__ xh,
                 ushort_t* __restrict__ Bh, ushort_t* __restrict__ Bl)
{
    const int b = blockIdx.x, t = threadIdx.x;
    // x -> bf16 (6250 blocks * 256 thr * 4 f32 = NN*DF exactly)
    size_t idx = ((size_t)b * 256 + t) * 4;
    float4 v = ld4(x + idx);
    unsigned p0 = rne16(v.x) | (rne16(v.y) << 16);
    unsigned p1 = rne16(v.z) | (rne16(v.w) << 16);
    uint2 pv; pv.x = p0; pv.y = p1;
    *(uint2*)(xh + idx) = pv;
    // W prep on blocks 0..255, threads 0..63
    if (b < 256 && t < 64) {
        const int m = b >> 5;
        const int nblk = (b >> 2) & 7;
        const int s = b & 3;
        const float* Wsrc = (m < 4) ? (W1 + (size_t)m * DF * DF)
                                    : (W2 + (size_t)(m - 4) * DF * DF);
        const int n = nblk * 16 + (t & 15);
        const int k0 = s * 32 + (t >> 4) * 8;
        size_t off = (size_t)m * (DF * DF) + ((size_t)(nblk * 4 + s) * 64 + t) * 8;
#pragma unroll
        for (int j = 0; j < 8; ++j) {
            float w = Wsrc[(size_t)(k0 + j) * DF + n];
            unsigned h, lo;
            bsplit(w, h, lo);
            Bh[off + j] = (ushort_t)h;
            Bl[off + j] = (ushort_t)lo;
        }
    }
}

// ---------------------------------------------------------------- SpMM: t = x + A@x (bf16 gather, f32 acc, hi/lo out)
template<int K>
static __device__ __forceinline__ void gatherK(const ushort_t* __restrict__ xh,
                                               const int* __restrict__ colidx,
                                               int e, int c2, float& ax, float& ay)
{
    unsigned v[K];
#pragma unroll
    for (int k = 0; k < K; ++k) {
        int j = colidx[e + k];
        v[k] = *(const unsigned*)(xh + (size_t)j * DF + c2);
    }
#pragma unroll
    for (int k = 0; k < K; ++k) {
        ax += __uint_as_float(v[k] << 16);
        ay += __uint_as_float(v[k] & 0xffff0000u);
    }
}

__global__ __launch_bounds__(256)
void spmm_kernel(const ushort_t* __restrict__ xh, const int* __restrict__ rowptr,
                 const int* __restrict__ colidx, ushort_t* __restrict__ th,
                 ushort_t* __restrict__ tl)
{
    const int lane = threadIdx.x & 63;
    const int i = __builtin_amdgcn_readfirstlane(blockIdx.x * 4 + (threadIdx.x >> 6));
    const int c2 = lane * 2;
    unsigned sv = *(const unsigned*)(xh + (size_t)i * DF + c2);
    float ax = __uint_as_float(sv << 16);
    float ay = __uint_as_float(sv & 0xffff0000u);
    int e = rowptr[i];
    const int e1 = rowptr[i + 1];
    for (; e + 16 <= e1; e += 16) gatherK<16>(xh, colidx, e, c2, ax, ay);
    if (e1 - e >= 8) { gatherK<8>(xh, colidx, e, c2, ax, ay); e += 8; }
    if (e1 - e >= 4) { gatherK<4>(xh, colidx, e, c2, ax, ay); e += 4; }
    if (e1 - e >= 2) { gatherK<2>(xh, colidx, e, c2, ax, ay); e += 2; }
    if (e1 - e >= 1) { gatherK<1>(xh, colidx, e, c2, ax, ay); }
    unsigned h0, l0, h1, l1;
    bsplit(ax, h0, l0);
    bsplit(ay, h1, l1);
    *(unsigned*)(th + (size_t)i * DF + c2) = h0 | (h1 << 16);
    *(unsigned*)(tl + (size_t)i * DF + c2) = l0 | (l1 << 16);
}

// ---------------------------------------------------------------- GEMM1: h = t@W1 + b1, fused BN stats
// 32 rows/wave (2 row-groups), A-frags direct from th/tl, 3-MFMA split precision
__global__ __launch_bounds__(256)
void gemm1_kernel(const ushort_t* __restrict__ th, const ushort_t* __restrict__ tl,
                  const ushort_t* __restrict__ Bh, const ushort_t* __restrict__ Bl,
                  const float* __restrict__ bias, float* __restrict__ C,
                  float* __restrict__ stats)
{
    __shared__ float red[2][DF];
    const int tid = threadIdx.x;
    const int lane = tid & 63;
    const int wave = tid >> 6;
    const int row0 = blockIdx.x * 128 + wave * 32;
    const int rA0 = row0 + (lane & 15);
    const int rAc0 = (rA0 < NN) ? rA0 : (NN - 1);
    const int rA1 = rA0 + 16;
    const int rAc1 = (rA1 < NN) ? rA1 : (NN - 1);
    const int kg = lane >> 4;

    if (tid < DF) { red[0][tid] = 0.f; red[1][tid] = 0.f; }
    __syncthreads();

    f32x4 acc0[8], acc1[8];
#pragma unroll
    for (int f = 0; f < 8; ++f) {
        acc0[f] = (f32x4){0.f, 0.f, 0.f, 0.f};
        acc1[f] = (f32x4){0.f, 0.f, 0.f, 0.f};
    }

    for (int s = 0; s < 4; ++s) {
        const int ko = s * 32 + kg * 8;
        bf16x8 ah0 = *(const bf16x8*)(th + (size_t)rAc0 * DF + ko);
        bf16x8 al0 = *(const bf16x8*)(tl + (size_t)rAc0 * DF + ko);
        bf16x8 ah1 = *(const bf16x8*)(th + (size_t)rAc1 * DF + ko);
        bf16x8 al1 = *(const bf16x8*)(tl + (size_t)rAc1 * DF + ko);
#pragma unroll
        for (int f = 0; f < 8; ++f) {
            const size_t boff = ((size_t)(f * 4 + s) * 64 + lane) * 8;
            bf16x8 bh = *(const bf16x8*)(Bh + boff);
            bf16x8 bl = *(const bf16x8*)(Bl + boff);
            acc0[f] = __builtin_amdgcn_mfma_f32_16x16x32_bf16(ah0, bh, acc0[f], 0, 0, 0);
            acc0[f] = __builtin_amdgcn_mfma_f32_16x16x32_bf16(al0, bh, acc0[f], 0, 0, 0);
            acc0[f] = __builtin_amdgcn_mfma_f32_16x16x32_bf16(ah0, bl, acc0[f], 0, 0, 0);
            acc1[f] = __builtin_amdgcn_mfma_f32_16x16x32_bf16(ah1, bh, acc1[f], 0, 0, 0);
            acc1[f] = __builtin_amdgcn_mfma_f32_16x16x32_bf16(al1, bh, acc1[f], 0, 0, 0);
            acc1[f] = __builtin_amdgcn_mfma_f32_16x16x32_bf16(ah1, bl, acc1[f], 0, 0, 0);
        }
    }

    const int colb = lane & 15;
    const int rb0 = row0 + kg * 4;
    const int rb1 = row0 + 16 + kg * 4;
#pragma unroll
    for (int f = 0; f < 8; ++f) {
        const int col = f * 16 + colb;
        const float bcol = bias[col];
        float sj = 0.f, qj = 0.f;
#pragma unroll
        for (int r = 0; r < 4; ++r) {
            int row = rb0 + r;
            if (row < NN) {
                float v = acc0[f][r] + bcol;
                C[(size_t)row * DF + col] = v;
                sj += v; qj += v * v;
            }
        }
#pragma unroll
        for (int r = 0; r < 4; ++r) {
            int row = rb1 + r;
            if (row < NN) {
                float v = acc1[f][r] + bcol;
                C[(size_t)row * DF + col] = v;
                sj += v; qj += v * v;
            }
        }
        atomicAdd(&red[0][col], sj);
        atomicAdd(&red[1][col], qj);
    }
    __syncthreads();
    if (tid < DF) {
        atomicAdd(&stats[tid], red[0][tid]);
        atomicAdd(&stats[DF + tid], red[1][tid]);
    }
}

// ---------------------------------------------------------------- GEMM2: x' = relu(bn(h))@W2 + b2, fused pool, bf16 out
__global__ __launch_bounds__(256)
void gemm2_kernel(const float* __restrict__ Hm, const ushort_t* __restrict__ Bh,
                  const ushort_t* __restrict__ Bl, const float* __restrict__ bias,
                  const float* __restrict__ gamma, const float* __restrict__ beta,
                  const float* __restrict__ stats, const int* __restrict__ batch,
                  float* __restrict__ zbuf, const int l, ushort_t* __restrict__ Xh)
{
    __shared__ float sscale[DF], sshift[DF];
    __shared__ float zslab[4][DF];
    __shared__ int sg0;
    const int tid = threadIdx.x;
    const int lane = tid & 63;
    const int wave = tid >> 6;
    const int brow0 = blockIdx.x * 128;
    const int row0 = brow0 + wave * 32;
    const int rA0 = row0 + (lane & 15);
    const int rAc0 = (rA0 < NN) ? rA0 : (NN - 1);
    const int rA1 = rA0 + 16;
    const int rAc1 = (rA1 < NN) ? rA1 : (NN - 1);
    const int kg = lane >> 4;

    if (tid < DF) {
        float s = stats[tid], q = stats[DF + tid];
        float mu = s * (1.f / NN);
        float var = q * (1.f / NN) - mu * mu;
        float sc = gamma[tid] * rsqrtf(var + BN_EPS);
        sscale[tid] = sc;
        sshift[tid] = beta[tid] - mu * sc;
    }
    if (tid == 0) sg0 = batch[brow0];
    for (int t = tid; t < 4 * DF; t += 256) (&zslab[0][0])[t] = 0.f;
    __syncthreads();

    f32x4 acc0[8], acc1[8];
#pragma unroll
    for (int f = 0; f < 8; ++f) {
        acc0[f] = (f32x4){0.f, 0.f, 0.f, 0.f};
        acc1[f] = (f32x4){0.f, 0.f, 0.f, 0.f};
    }

    for (int s = 0; s < 4; ++s) {
        const int ko = s * 32 + kg * 8;
        f32x4 sc0 = *(const f32x4*)&sscale[ko];
        f32x4 sc1 = *(const f32x4*)&sscale[ko + 4];
        f32x4 sh0 = *(const f32x4*)&sshift[ko];
        f32x4 sh1 = *(const f32x4*)&sshift[ko + 4];
        bf16x8 ah0, al0, ah1, al1;
        {
            const float* ap = Hm + (size_t)rAc0 * DF + ko;
            f32x4 a0 = *(const f32x4*)ap;
            f32x4 a1 = *(const f32x4*)(ap + 4);
#pragma unroll
            for (int j = 0; j < 4; ++j) {
                unsigned h, lo;
                float v0 = fmaxf(0.f, a0[j] * sc0[j] + sh0[j]);
                float v1 = fmaxf(0.f, a1[j] * sc1[j] + sh1[j]);
                bsplit(v0, h, lo); ah0[j] = h; al0[j] = lo;
                bsplit(v1, h, lo); ah0[4 + j] = h; al0[4 + j] = lo;
            }
        }
        {
            const float* ap = Hm + (size_t)rAc1 * DF + ko;
            f32x4 a0 = *(const f32x4*)ap;
            f32x4 a1 = *(const f32x4*)(ap + 4);
#pragma unroll
            for (int j = 0; j < 4; ++j) {
                unsigned h, lo;
                float v0 = fmaxf(0.f, a0[j] * sc0[j] + sh0[j]);
                float v1 = fmaxf(0.f, a1[j] * sc1[j] + sh1[j]);
                bsplit(v0, h, lo); ah1[j] = h; al1[j] = lo;
                bsplit(v1, h, lo); ah1[4 + j] = h; al1[4 + j] = lo;
            }
        }
#pragma unroll
        for (int f = 0; f < 8; ++f) {
            const size_t boff = ((size_t)(f * 4 + s) * 64 + lane) * 8;
            bf16x8 bh = *(const bf16x8*)(Bh + boff);
            bf16x8 bl = *(const bf16x8*)(Bl + boff);
            acc0[f] = __builtin_amdgcn_mfma_f32_16x16x32_bf16(ah0, bh, acc0[f], 0, 0, 0);
            acc0[f] = __builtin_amdgcn_mfma_f32_16x16x32_bf16(al0, bh, acc0[f], 0, 0, 0);
            acc0[f] = __builtin_amdgcn_mfma_f32_16x16x32_bf16(ah0, bl, acc0[f], 0, 0, 0);
            acc1[f] = __builtin_amdgcn_mfma_f32_16x16x32_bf16(ah1, bh, acc1[f], 0, 0, 0);
            acc1[f] = __builtin_amdgcn_mfma_f32_16x16x32_bf16(al1, bh, acc1[f], 0, 0, 0);
            acc1[f] = __builtin_amdgcn_mfma_f32_16x16x32_bf16(ah1, bl, acc1[f], 0, 0, 0);
        }
    }

    const int colb = lane & 15;
    const int g0 = sg0;
#pragma unroll
    for (int rg = 0; rg < 2; ++rg) {
        const int rbase = row0 + rg * 16 + kg * 4;
        int g_[4]; bool val[4];
#pragma unroll
        for (int r = 0; r < 4; ++r) {
            int row = rbase + r;
            val[r] = row < NN;
            g_[r] = batch[val[r] ? row : (NN - 1)];
        }
        const bool uni = val[3] && (g_[0] == g_[3]);
#pragma unroll
        for (int f = 0; f < 8; ++f) {
            const int col = f * 16 + colb;
            const float bcol = bias[col];
            const f32x4 a = rg ? acc1[f] : acc0[f];
            float vv[4];
#pragma unroll
            for (int r = 0; r < 4; ++r) vv[r] = a[r] + bcol;
#pragma unroll
            for (int r = 0; r < 4; ++r)
                if (val[r]) Xh[(size_t)(rbase + r) * DF + col] = (ushort_t)rne16(vv[r]);
            if (uni) {
                float sum = (vv[0] + vv[1]) + (vv[2] + vv[3]);
                int idx = g_[0] - g0;
                if ((unsigned)idx < 4u) atomicAdd(&zslab[idx][col], sum);
                else atomicAdd(&zbuf[(size_t)g_[0] * (NL * DF) + l * DF + col], sum);
            } else {
#pragma unroll
                for (int r = 0; r < 4; ++r) if (val[r]) {
                    int idx = g_[r] - g0;
                    if ((unsigned)idx < 4u) atomicAdd(&zslab[idx][col], vv[r]);
                    else atomicAdd(&zbuf[(size_t)g_[r] * (NL * DF) + l * DF + col], vv[r]);
                }
            }
        }
    }
    __syncthreads();
    int lastrow = brow0 + 127; if (lastrow >= NN) lastrow = NN - 1;
    int ns = batch[lastrow] - g0 + 1; if (ns > 4) ns = 4;
    if (tid < DF)
        for (int sl = 0; sl < ns; ++sl)
            atomicAdd(&zbuf[(size_t)(g0 + sl) * (NL * DF) + l * DF + tid], zslab[sl][tid]);
}

// ---------------------------------------------------------------- final MLP
__global__ __launch_bounds__(128)
void p1_kernel(const float* __restrict__ z, const float* __restrict__ Wp1,
               const float* __restrict__ bp1, float* __restrict__ z1)
{
    const int g = blockIdx.x;
    const int f = threadIdx.x;
    const float* zr = z + (size_t)g * (NL * DF);
    float a0 = 0.f, a1 = 0.f, a2 = 0.f, a3 = 0.f;
#pragma unroll 4
    for (int k = 0; k < NL * DF; k += 4) {
        float4 zv = ld4(zr + k);
        a0 = fmaf(zv.x, Wp1[(size_t)(k + 0) * DF + f], a0);
        a1 = fmaf(zv.y, Wp1[(size_t)(k + 1) * DF + f], a1);
        a2 = fmaf(zv.z, Wp1[(size_t)(k + 2) * DF + f], a2);
        a3 = fmaf(zv.w, Wp1[(size_t)(k + 3) * DF + f], a3);
    }
    z1[(size_t)g * DF + f] = (a0 + a1) + (a2 + a3) + bp1[f];
}

// pbn fused into p3: every block recomputes the 128-col stats (z1 is L2-hot)
__global__ __launch_bounds__(128)
void p23_kernel(const float* __restrict__ z1, const float* __restrict__ gp,
                const float* __restrict__ bp, const float* __restrict__ Wp2,
                const float* __restrict__ bp2, float* __restrict__ out)
{
    __shared__ float a[DF];
    const int g = blockIdx.x;
    const int f = threadIdx.x;
    float s = 0.f, q = 0.f;
#pragma unroll 8
    for (int r = 0; r < NG; ++r) {
        float v = z1[(size_t)r * DF + f];
        s += v; q += v * v;
    }
    float mu = s * (1.f / NG);
    float var = q * (1.f / NG) - mu * mu;
    float sc = gp[f] * rsqrtf(var + BN_EPS);
    float sh = bp[f] - mu * sc;
    float v = z1[(size_t)g * DF + f];
    a[f] = fmaxf(0.f, v * sc + sh);
    __syncthreads();
    if (f < NOUTC) {
        float acc = bp2[f];
        for (int k = 0; k < DF; ++k)
            acc = fmaf(a[k], Wp2[k * NOUTC + f], acc);
        out[(size_t)g * NOUTC + f] = acc;
    }
}

// ---------------------------------------------------------------- launch
extern "C" void kernel_launch(void* const* d_in, const int* in_sizes, int n_in,
                              void* d_out, int out_size, void* d_ws, size_t ws_size,
                              hipStream_t stream)
{
    const float* d_x   = (const float*)d_in[0];
    const int*   d_ei  = (const int*)d_in[1];
    const int*   d_bat = (const int*)d_in[2];
    const float* d_W1  = (const float*)d_in[4];
    const float* d_b1  = (const float*)d_in[5];
    const float* d_gm  = (const float*)d_in[6];
    const float* d_bt  = (const float*)d_in[7];
    const float* d_W2  = (const float*)d_in[8];
    const float* d_b2  = (const float*)d_in[9];
    const float* d_Wp1 = (const float*)d_in[10];
    const float* d_bp1 = (const float*)d_in[11];
    const float* d_gp  = (const float*)d_in[12];
    const float* d_bp  = (const float*)d_in[13];
    const float* d_Wp2 = (const float*)d_in[14];
    const float* d_bp2 = (const float*)d_in[15];
    float* out = (float*)d_out;

    char* ws = (char*)d_ws;
    // ---- zero region (one memset): zbuf | rowptr | stats4
    float*    zbuf    = (float*)(ws + 0);          // 256*512 f32 = 524288 B
    int*      rowptr  = (int*)(ws + 524288);       // (NN+1) ints = 200004 B
    float*    stats4  = (float*)(ws + 724292);     // 4*256 f32 = 4096 B
    const size_t zero_len = 728388;
    // ---- rest
    int*      rank    = (int*)(ws + 728576);       // NE ints (ends 3928576)
    int*      colidx  = (int*)(ws + 3928576);      // NE ints (ends 7128576)
    int*      blksums = (int*)(ws + 7128576);      // 64 ints
    float*    z1buf   = (float*)(ws + 7129088);    // NG*128 f32 (ends 7260160)
    ushort_t* Whi     = (ushort_t*)(ws + 7260160); // 8*16384 bf16 (ends 7522304)
    ushort_t* Wlo     = (ushort_t*)(ws + 7522304); // (ends 7784448)
    ushort_t* xh      = (ushort_t*)(ws + 7784448); // NN*128 bf16 (ends 20584448)
    ushort_t* th      = (ushort_t*)(ws + 20584448);// (ends 33384448)
    ushort_t* tl      = (ushort_t*)(ws + 33384448);// (ends 46184448)
    float*    hbuf    = (float*)(ws + 46184448);   // NN*128 f32 (ends 71784448)

    hipMemsetAsync(ws, 0, zero_len, stream);

    count_kernel<<<(NE / 4 + 255) / 256, 256, 0, stream>>>(d_ei, rowptr, rank);
    scan1_kernel<<<49, 256, 0, stream>>>(rowptr, blksums);
    scan3_kernel<<<(NN + 255) / 256, 256, 0, stream>>>(rowptr, blksums);
    scatter_kernel<<<(NE / 4 + 255) / 256, 256, 0, stream>>>(d_ei, rowptr, rank, colidx);
    prep_kernel<<<NN * DF / 1024, 256, 0, stream>>>(d_x, d_W1, d_W2, xh, Whi, Wlo);

    const int gemm_grid = (NN + 127) / 128;   // 391
    for (int l = 0; l < NL; ++l) {
        spmm_kernel<<<(NN + 3) / 4, 256, 0, stream>>>(xh, rowptr, colidx, th, tl);
        gemm1_kernel<<<gemm_grid, 256, 0, stream>>>(th, tl,
                                                    Whi + (size_t)l * DF * DF,
                                                    Wlo + (size_t)l * DF * DF,
                                                    d_b1 + l * DF, hbuf,
                                                    stats4 + l * 256);
        gemm2_kernel<<<gemm_grid, 256, 0, stream>>>(hbuf,
                                                    Whi + (size_t)(4 + l) * DF * DF,
                                                    Wlo + (size_t)(4 + l) * DF * DF,
                                                    d_b2 + l * DF, d_gm + l * DF,
                                                    d_bt + l * DF, stats4 + l * 256,
                                                    d_bat, zbuf, l, xh);
    }
    p1_kernel<<<NG, 128, 0, stream>>>(zbuf, d_Wp1, d_bp1, z1buf);
    p23_kernel<<<NG, 128, 0, stream>>>(z1buf, d_gp, d_bp, d_Wp2, d_bp2, out);
}